// Round 1
// baseline (408.882 us; speedup 1.0000x reference)
//
#include <hip/hip_runtime.h>

#define S_LEN 2048
#define EDIM  1024
#define HEADS 16
#define DHEAD 64

typedef __attribute__((ext_vector_type(8))) short bf16x8;
typedef __attribute__((ext_vector_type(4))) short short4v;
typedef __attribute__((ext_vector_type(4))) float f32x4;

__device__ inline unsigned short f2bf(float f) {
    unsigned int u = __float_as_uint(f);
    unsigned int r = (u + 0x7FFFu + ((u >> 16) & 1u)) >> 16;
    return (unsigned short)r;
}

// ---------------- X fp32 -> bf16 ----------------
__global__ void k_convert_x(const float* __restrict__ x, short* __restrict__ xb, int n4) {
    int i = blockIdx.x * blockDim.x + threadIdx.x;
    if (i >= n4) return;
    f32x4 v = ((const f32x4*)x)[i];
    short4v o;
    o[0] = (short)f2bf(v[0]); o[1] = (short)f2bf(v[1]);
    o[2] = (short)f2bf(v[2]); o[3] = (short)f2bf(v[3]);
    ((short4v*)xb)[i] = o;
}

// ---------------- tiled transpose + fp32->bf16: in[R][C] -> out[C][R], batched over z ----------------
__global__ void k_transpose_cvt(const float* __restrict__ in, short* __restrict__ out, int R, int C) {
    __shared__ float tile[32][33];
    const int b = blockIdx.z;
    in  += (size_t)b * R * C;
    out += (size_t)b * R * C;
    const int c0 = blockIdx.x * 32, r0 = blockIdx.y * 32;
    #pragma unroll
    for (int yy = 0; yy < 4; ++yy) {
        int r = r0 + threadIdx.y + yy * 8, c = c0 + threadIdx.x;
        tile[threadIdx.y + yy * 8][threadIdx.x] = (r < R && c < C) ? in[(size_t)r * C + c] : 0.f;
    }
    __syncthreads();
    #pragma unroll
    for (int yy = 0; yy < 4; ++yy) {
        int c = c0 + threadIdx.y + yy * 8, r = r0 + threadIdx.x;
        if (c < C && r < R) out[(size_t)c * R + r] = (short)f2bf(tile[threadIdx.x][threadIdx.y + yy * 8]);
    }
}

// ---------------- 128x128 MFMA tile: A row-major [M][lda], Bt row-major [N][ldb] (k contiguous) ----------------
__device__ inline void gemm128(const short* __restrict__ A, int lda,
                               const short* __restrict__ Bt, int ldb,
                               int K, f32x4 acc[4][4]) {
    const int lane = threadIdx.x & 63;
    const int wave = threadIdx.x >> 6;
    const int wr = (wave >> 1) * 64;
    const int wc = (wave & 1) * 64;
    const int rl = lane & 15, g = lane >> 4;
    for (int k0 = 0; k0 < K; k0 += 32) {
        bf16x8 af[4], bf[4];
        #pragma unroll
        for (int f = 0; f < 4; ++f)
            af[f] = *(const bf16x8*)&A[(size_t)(wr + f * 16 + rl) * lda + k0 + g * 8];
        #pragma unroll
        for (int f = 0; f < 4; ++f)
            bf[f] = *(const bf16x8*)&Bt[(size_t)(wc + f * 16 + rl) * ldb + k0 + g * 8];
        #pragma unroll
        for (int i = 0; i < 4; ++i)
            #pragma unroll
            for (int j = 0; j < 4; ++j)
                acc[i][j] = __builtin_amdgcn_mfma_f32_16x16x32_bf16(af[i], bf[j], acc[i][j], 0, 0, 0);
    }
}

// ---------------- QKV projection GEMM ----------------
// grid.y: [0,16) Q tiles, [16,32) K tiles, [32,40) V tiles
__global__ __launch_bounds__(256) void k_gemm_qkv(
        const short* __restrict__ Xb,
        const short* __restrict__ WqT, const short* __restrict__ WkT, const short* __restrict__ WvT,
        const float* __restrict__ bq, const float* __restrict__ bk, const float* __restrict__ bv,
        short* __restrict__ Qh, short* __restrict__ Kh, short* __restrict__ Vt) {
    const int mbase = blockIdx.x * 128;
    const int y = blockIdx.y;
    const short* Bt; const float* bias; int nbase; int which;
    if (y < 16)      { which = 0; Bt = WqT; bias = bq; nbase = y * 128; }
    else if (y < 32) { which = 1; Bt = WkT; bias = bk; nbase = (y - 16) * 128; }
    else             { which = 2; Bt = WvT; bias = bv; nbase = (y - 32) * 128; }

    f32x4 acc[4][4];
    #pragma unroll
    for (int i = 0; i < 4; ++i)
        #pragma unroll
        for (int j = 0; j < 4; ++j)
            acc[i][j] = (f32x4){0.f, 0.f, 0.f, 0.f};

    gemm128(Xb + (size_t)mbase * EDIM, EDIM, Bt + (size_t)nbase * EDIM, EDIM, EDIM, acc);

    const int lane = threadIdx.x & 63, wave = threadIdx.x >> 6;
    const int wr = (wave >> 1) * 64, wc = (wave & 1) * 64;
    const int rl = lane & 15, g = lane >> 4;
    #pragma unroll
    for (int i = 0; i < 4; ++i)
        #pragma unroll
        for (int j = 0; j < 4; ++j)
            #pragma unroll
            for (int jj = 0; jj < 4; ++jj) {
                int s = mbase + wr + i * 16 + g * 4 + jj;
                int n = nbase + wc + j * 16 + rl;
                float v = acc[i][j][jj] + bias[n];
                short b16 = (short)f2bf(v);
                if (which == 0)      Qh[((size_t)(n >> 7) * S_LEN + s) * 128 + (n & 127)] = b16;
                else if (which == 1) Kh[((size_t)(n >> 7) * S_LEN + s) * 128 + (n & 127)] = b16;
                else                 Vt[(size_t)n * S_LEN + s] = b16;
            }
}

// ---------------- differential flash attention ----------------
// grid (S/64, H); 4 waves, each wave owns 16 q rows; two online softmaxes share V
__global__ __launch_bounds__(256) void k_attn(
        const short* __restrict__ Qh, const short* __restrict__ Kh,
        const short* __restrict__ Vt, const float* __restrict__ lam_p,
        short* __restrict__ Ocat) {
    __shared__ __align__(16) short Pl[4][2][16][72];   // padded 64->72 to break bank conflicts
    const int lane = threadIdx.x & 63, wave = threadIdx.x >> 6;
    const int rl = lane & 15, g = lane >> 4;
    const int h = blockIdx.y;
    const int qbase = blockIdx.x * 64 + wave * 16;
    const float SC = 0.125f * 1.44269504088896f;   // 1/sqrt(64) * log2(e)

    const short* Qp = Qh + (size_t)h * S_LEN * 128;
    const short* Kp = Kh + (size_t)h * S_LEN * 128;
    const short* Vp = Vt + (size_t)h * DHEAD * S_LEN;

    bf16x8 qf[2][2];
    #pragma unroll
    for (int p = 0; p < 2; ++p)
        #pragma unroll
        for (int kc = 0; kc < 2; ++kc)
            qf[p][kc] = *(const bf16x8*)&Qp[(size_t)(qbase + rl) * 128 + p * 64 + kc * 32 + g * 8];

    f32x4 acc[2][4];
    float m[2][4], l[2][4];
    #pragma unroll
    for (int p = 0; p < 2; ++p) {
        #pragma unroll
        for (int t = 0; t < 4; ++t) acc[p][t] = (f32x4){0.f, 0.f, 0.f, 0.f};
        #pragma unroll
        for (int jj = 0; jj < 4; ++jj) { m[p][jj] = -INFINITY; l[p][jj] = 0.f; }
    }

    for (int kv0 = 0; kv0 < S_LEN; kv0 += 64) {
        // scores for both pairs: sc[p][t], t = kv subtile of 16
        f32x4 sc[2][4];
        #pragma unroll
        for (int t = 0; t < 4; ++t)
            #pragma unroll
            for (int p = 0; p < 2; ++p) {
                f32x4 z = (f32x4){0.f, 0.f, 0.f, 0.f};
                #pragma unroll
                for (int kc = 0; kc < 2; ++kc) {
                    bf16x8 kf = *(const bf16x8*)&Kp[(size_t)(kv0 + t * 16 + rl) * 128 + p * 64 + kc * 32 + g * 8];
                    z = __builtin_amdgcn_mfma_f32_16x16x32_bf16(qf[p][kc], kf, z, 0, 0, 0);
                }
                sc[p][t] = z * SC;
            }

        #pragma unroll
        for (int p = 0; p < 2; ++p) {
            float bm[4];
            #pragma unroll
            for (int jj = 0; jj < 4; ++jj)
                bm[jj] = fmaxf(fmaxf(sc[p][0][jj], sc[p][1][jj]), fmaxf(sc[p][2][jj], sc[p][3][jj]));
            #pragma unroll
            for (int off = 1; off <= 8; off <<= 1)
                #pragma unroll
                for (int jj = 0; jj < 4; ++jj)
                    bm[jj] = fmaxf(bm[jj], __shfl_xor(bm[jj], off, 64));
            float mn[4];
            #pragma unroll
            for (int jj = 0; jj < 4; ++jj) {
                mn[jj] = fmaxf(m[p][jj], bm[jj]);
                float resc = exp2f(m[p][jj] - mn[jj]);
                m[p][jj] = mn[jj];
                l[p][jj] *= resc;
                #pragma unroll
                for (int t = 0; t < 4; ++t) acc[p][t][jj] *= resc;
            }
            float rsum[4] = {0.f, 0.f, 0.f, 0.f};
            #pragma unroll
            for (int t = 0; t < 4; ++t)
                #pragma unroll
                for (int jj = 0; jj < 4; ++jj) {
                    float pv = exp2f(sc[p][t][jj] - mn[jj]);
                    rsum[jj] += pv;
                    Pl[wave][p][g * 4 + jj][t * 16 + rl] = (short)f2bf(pv);
                }
            #pragma unroll
            for (int off = 1; off <= 8; off <<= 1)
                #pragma unroll
                for (int jj = 0; jj < 4; ++jj)
                    rsum[jj] += __shfl_xor(rsum[jj], off, 64);
            #pragma unroll
            for (int jj = 0; jj < 4; ++jj) l[p][jj] += rsum[jj];
        }
        __syncthreads();

        // O += P @ V
        #pragma unroll
        for (int p = 0; p < 2; ++p)
            #pragma unroll
            for (int kc = 0; kc < 2; ++kc) {
                bf16x8 pa = *(const bf16x8*)&Pl[wave][p][rl][kc * 32 + g * 8];
                #pragma unroll
                for (int t = 0; t < 4; ++t) {
                    bf16x8 vf = *(const bf16x8*)&Vp[(size_t)(t * 16 + rl) * S_LEN + kv0 + kc * 32 + g * 8];
                    acc[p][t] = __builtin_amdgcn_mfma_f32_16x16x32_bf16(pa, vf, acc[p][t], 0, 0, 0);
                }
            }
        __syncthreads();
    }

    const float lam = lam_p[0];
    #pragma unroll
    for (int t = 0; t < 4; ++t)
        #pragma unroll
        for (int jj = 0; jj < 4; ++jj) {
            float o = acc[0][t][jj] / l[0][jj] - lam * acc[1][t][jj] / l[1][jj];
            int s = qbase + g * 4 + jj;
            Ocat[(size_t)s * 1024 + h * 64 + t * 16 + rl] = (short)f2bf(o);
        }
}

// ---------------- output projection GEMM ----------------
__global__ __launch_bounds__(256) void k_gemm_out(
        const short* __restrict__ Ocat, const short* __restrict__ WoT,
        const float* __restrict__ bo, float* __restrict__ Yws) {
    const int mbase = blockIdx.x * 128, nbase = blockIdx.y * 128;
    f32x4 acc[4][4];
    #pragma unroll
    for (int i = 0; i < 4; ++i)
        #pragma unroll
        for (int j = 0; j < 4; ++j)
            acc[i][j] = (f32x4){0.f, 0.f, 0.f, 0.f};

    gemm128(Ocat + (size_t)mbase * 1024, 1024, WoT + (size_t)nbase * 1024, 1024, 1024, acc);

    const int lane = threadIdx.x & 63, wave = threadIdx.x >> 6;
    const int wr = (wave >> 1) * 64, wc = (wave & 1) * 64;
    const int rl = lane & 15, g = lane >> 4;
    #pragma unroll
    for (int i = 0; i < 4; ++i)
        #pragma unroll
        for (int j = 0; j < 4; ++j)
            #pragma unroll
            for (int jj = 0; jj < 4; ++jj) {
                int s = mbase + wr + i * 16 + g * 4 + jj;
                int e = nbase + wc + j * 16 + rl;
                Yws[(size_t)s * 1024 + e] = acc[i][j][jj] + bo[e];
            }
}

// ---------------- LayerNorm + final scale ----------------
__global__ __launch_bounds__(256) void k_ln(
        const float* __restrict__ Yws, const float* __restrict__ gamma,
        const float* __restrict__ beta, float* __restrict__ out) {
    const int s = blockIdx.x;
    const int tid = threadIdx.x;
    f32x4 y = ((const f32x4*)(Yws + (size_t)s * 1024))[tid];
    float sum = y[0] + y[1] + y[2] + y[3];
    float sq  = y[0]*y[0] + y[1]*y[1] + y[2]*y[2] + y[3]*y[3];
    #pragma unroll
    for (int off = 1; off < 64; off <<= 1) {
        sum += __shfl_xor(sum, off, 64);
        sq  += __shfl_xor(sq,  off, 64);
    }
    __shared__ float ls[2][4];
    const int wave = tid >> 6, lane = tid & 63;
    if (lane == 0) { ls[0][wave] = sum; ls[1][wave] = sq; }
    __syncthreads();
    sum = ls[0][0] + ls[0][1] + ls[0][2] + ls[0][3];
    sq  = ls[1][0] + ls[1][1] + ls[1][2] + ls[1][3];
    const float mu = sum * (1.f / 1024.f);
    const float var = sq * (1.f / 1024.f) - mu * mu;
    const float rstd = rsqrtf(var + 1e-5f);
    f32x4 gg = ((const f32x4*)gamma)[tid];
    f32x4 bb = ((const f32x4*)beta)[tid];
    f32x4 o;
    #pragma unroll
    for (int k = 0; k < 4; ++k)
        o[k] = ((y[k] - mu) * rstd * gg[k] + bb[k]) * 0.2f;
    ((f32x4*)(out + (size_t)s * 1024))[tid] = o;
}

extern "C" void kernel_launch(void* const* d_in, const int* in_sizes, int n_in,
                              void* d_out, int out_size, void* d_ws, size_t ws_size,
                              hipStream_t stream) {
    const float* X     = (const float*)d_in[0];
    const float* Wq    = (const float*)d_in[1];
    const float* bq    = (const float*)d_in[2];
    const float* Wk    = (const float*)d_in[3];
    const float* bk    = (const float*)d_in[4];
    const float* Wv    = (const float*)d_in[5];
    const float* bv    = (const float*)d_in[6];
    const float* Wo    = (const float*)d_in[7];
    const float* bo    = (const float*)d_in[8];
    const float* gamma = (const float*)d_in[9];
    const float* beta  = (const float*)d_in[10];
    const float* lam   = (const float*)d_in[11];
    float* out = (float*)d_out;

    char* ws = (char*)d_ws;
    const size_t MB = 1u << 20;
    short* Xb  = (short*)(ws + 0);        // 4MB (dead after qkv gemm)
    short* WqT = (short*)(ws + 4 * MB);   // 4MB (dead after qkv gemm)
    short* WkT = (short*)(ws + 8 * MB);   // 4MB
    short* WvT = (short*)(ws + 12 * MB);  // 2MB
    short* WoT = (short*)(ws + 14 * MB);  // 2MB
    short* Qh  = (short*)(ws + 16 * MB);  // 8MB
    short* Kh  = (short*)(ws + 24 * MB);  // 8MB
    short* Vt  = (short*)(ws + 32 * MB);  // 4MB
    short* Oc  = (short*)(ws + 36 * MB);  // 4MB
    float* Yws = (float*)(ws + 0);        // 8MB, aliases Xb+WqT (both dead by then)

    k_convert_x<<<dim3(2048), dim3(256), 0, stream>>>(X, Xb, (S_LEN * EDIM) / 4);
    k_transpose_cvt<<<dim3(4, 32, 16), dim3(32, 8), 0, stream>>>(Wq, WqT, 1024, 128);
    k_transpose_cvt<<<dim3(4, 32, 16), dim3(32, 8), 0, stream>>>(Wk, WkT, 1024, 128);
    k_transpose_cvt<<<dim3(2, 32, 16), dim3(32, 8), 0, stream>>>(Wv, WvT, 1024, 64);
    k_transpose_cvt<<<dim3(32, 32, 1), dim3(32, 8), 0, stream>>>(Wo, WoT, 1024, 1024);
    k_gemm_qkv<<<dim3(16, 40), dim3(256), 0, stream>>>(Xb, WqT, WkT, WvT, bq, bk, bv, Qh, Kh, Vt);
    k_attn<<<dim3(32, 16), dim3(256), 0, stream>>>(Qh, Kh, Vt, lam, Oc);
    k_gemm_out<<<dim3(16, 8), dim3(256), 0, stream>>>(Oc, WoT, bo, Yws);
    k_ln<<<dim3(2048), dim3(256), 0, stream>>>(Yws, gamma, beta, out);
}

// Round 2
// 382.424 us; speedup vs baseline: 1.0692x; 1.0692x over previous
//
#include <hip/hip_runtime.h>

#define S_LEN 2048
#define EDIM  1024
#define HEADS 16
#define DHEAD 64

typedef __attribute__((ext_vector_type(8))) short bf16x8;
typedef __attribute__((ext_vector_type(4))) short short4v;
typedef __attribute__((ext_vector_type(4))) float f32x4;

__device__ inline unsigned short f2bf(float f) {
    unsigned int u = __float_as_uint(f);
    unsigned int r = (u + 0x7FFFu + ((u >> 16) & 1u)) >> 16;
    return (unsigned short)r;
}

// ---------------- X fp32 -> bf16 ----------------
__global__ void k_convert_x(const float* __restrict__ x, short* __restrict__ xb, int n4) {
    int i = blockIdx.x * blockDim.x + threadIdx.x;
    if (i >= n4) return;
    f32x4 v = ((const f32x4*)x)[i];
    short4v o;
    o[0] = (short)f2bf(v[0]); o[1] = (short)f2bf(v[1]);
    o[2] = (short)f2bf(v[2]); o[3] = (short)f2bf(v[3]);
    ((short4v*)xb)[i] = o;
}

// ---------------- tiled transpose + fp32->bf16: in[R][C] -> out[C][R], batched over z ----------------
__global__ void k_transpose_cvt(const float* __restrict__ in, short* __restrict__ out, int R, int C) {
    __shared__ float tile[32][33];
    const int b = blockIdx.z;
    in  += (size_t)b * R * C;
    out += (size_t)b * R * C;
    const int c0 = blockIdx.x * 32, r0 = blockIdx.y * 32;
    #pragma unroll
    for (int yy = 0; yy < 4; ++yy) {
        int r = r0 + threadIdx.y + yy * 8, c = c0 + threadIdx.x;
        tile[threadIdx.y + yy * 8][threadIdx.x] = (r < R && c < C) ? in[(size_t)r * C + c] : 0.f;
    }
    __syncthreads();
    #pragma unroll
    for (int yy = 0; yy < 4; ++yy) {
        int c = c0 + threadIdx.y + yy * 8, r = r0 + threadIdx.x;
        if (c < C && r < R) out[(size_t)c * R + r] = (short)f2bf(tile[threadIdx.x][threadIdx.y + yy * 8]);
    }
}

// ---------------- 128x128 MFMA tile: A row-major [M][lda], Bt row-major [N][ldb] (k contiguous) ----------------
__device__ inline void gemm128(const short* __restrict__ A, int lda,
                               const short* __restrict__ Bt, int ldb,
                               int K, f32x4 acc[4][4]) {
    const int lane = threadIdx.x & 63;
    const int wave = threadIdx.x >> 6;
    const int wr = (wave >> 1) * 64;
    const int wc = (wave & 1) * 64;
    const int rl = lane & 15, g = lane >> 4;
    for (int k0 = 0; k0 < K; k0 += 32) {
        bf16x8 af[4], bf[4];
        #pragma unroll
        for (int f = 0; f < 4; ++f)
            af[f] = *(const bf16x8*)&A[(size_t)(wr + f * 16 + rl) * lda + k0 + g * 8];
        #pragma unroll
        for (int f = 0; f < 4; ++f)
            bf[f] = *(const bf16x8*)&Bt[(size_t)(wc + f * 16 + rl) * ldb + k0 + g * 8];
        #pragma unroll
        for (int i = 0; i < 4; ++i)
            #pragma unroll
            for (int j = 0; j < 4; ++j)
                acc[i][j] = __builtin_amdgcn_mfma_f32_16x16x32_bf16(af[i], bf[j], acc[i][j], 0, 0, 0);
    }
}

// ---------------- QKV projection GEMM ----------------
// grid.y: [0,16) Q tiles, [16,32) K tiles, [32,40) V tiles
__global__ __launch_bounds__(256) void k_gemm_qkv(
        const short* __restrict__ Xb,
        const short* __restrict__ WqT, const short* __restrict__ WkT, const short* __restrict__ WvT,
        const float* __restrict__ bq, const float* __restrict__ bk, const float* __restrict__ bv,
        short* __restrict__ Qh, short* __restrict__ Kh, short* __restrict__ Vt) {
    const int mbase = blockIdx.x * 128;
    const int y = blockIdx.y;
    const short* Bt; const float* bias; int nbase; int which;
    if (y < 16)      { which = 0; Bt = WqT; bias = bq; nbase = y * 128; }
    else if (y < 32) { which = 1; Bt = WkT; bias = bk; nbase = (y - 16) * 128; }
    else             { which = 2; Bt = WvT; bias = bv; nbase = (y - 32) * 128; }

    f32x4 acc[4][4];
    #pragma unroll
    for (int i = 0; i < 4; ++i)
        #pragma unroll
        for (int j = 0; j < 4; ++j)
            acc[i][j] = (f32x4){0.f, 0.f, 0.f, 0.f};

    gemm128(Xb + (size_t)mbase * EDIM, EDIM, Bt + (size_t)nbase * EDIM, EDIM, EDIM, acc);

    const int lane = threadIdx.x & 63, wave = threadIdx.x >> 6;
    const int wr = (wave >> 1) * 64, wc = (wave & 1) * 64;
    const int rl = lane & 15, g = lane >> 4;
    #pragma unroll
    for (int i = 0; i < 4; ++i)
        #pragma unroll
        for (int j = 0; j < 4; ++j)
            #pragma unroll
            for (int jj = 0; jj < 4; ++jj) {
                int s = mbase + wr + i * 16 + g * 4 + jj;
                int n = nbase + wc + j * 16 + rl;
                float v = acc[i][j][jj] + bias[n];
                short b16 = (short)f2bf(v);
                if (which == 0)      Qh[((size_t)(n >> 7) * S_LEN + s) * 128 + (n & 127)] = b16;
                else if (which == 1) Kh[((size_t)(n >> 7) * S_LEN + s) * 128 + (n & 127)] = b16;
                else                 Vt[(size_t)n * S_LEN + s] = b16;
            }
}

// ---------------- differential flash attention, v2 ----------------
// grid (S/64, H); 4 independent waves (no barriers), each wave owns 16 q rows.
// Swapped QK^T: mfma(K,Q) puts each q-row's scores lane-local -> 2-step shuffle
// reduce, packed b32 P writes, defer-max (T13, THR=8 in exp2 domain).
__global__ __launch_bounds__(256) void k_attn(
        const short* __restrict__ Qh, const short* __restrict__ Kh,
        const short* __restrict__ Vt, const float* __restrict__ lam_p,
        short* __restrict__ Ocat) {
    __shared__ __align__(16) unsigned short Pl[4][2][16][64];  // 16KB, wave-private slices
    const int lane = threadIdx.x & 63, wave = threadIdx.x >> 6;
    const int rl = lane & 15, g = lane >> 4;
    const int h = blockIdx.y;
    const int qbase = blockIdx.x * 64 + wave * 16;
    const float SC = 0.125f * 1.44269504088896f;   // 1/sqrt(64) * log2(e)
    const int swz = (rl & 7) << 4;                 // XOR byte-swizzle within 128B row

    const short* Qp = Qh + (size_t)h * S_LEN * 128;
    const short* Kp = Kh + (size_t)h * S_LEN * 128;
    const short* Vp = Vt + (size_t)h * DHEAD * S_LEN;
    char* Pb0 = (char*)&Pl[wave][0][0][0];
    char* Pb1 = (char*)&Pl[wave][1][0][0];

    bf16x8 qf[2][2];
    #pragma unroll
    for (int p = 0; p < 2; ++p)
        #pragma unroll
        for (int kc = 0; kc < 2; ++kc)
            qf[p][kc] = *(const bf16x8*)&Qp[(size_t)(qbase + rl) * 128 + p * 64 + kc * 32 + g * 8];

    f32x4 acc[2][4];
    float m[2], l[2];
    #pragma unroll
    for (int p = 0; p < 2; ++p) {
        #pragma unroll
        for (int t = 0; t < 4; ++t) acc[p][t] = (f32x4){0.f, 0.f, 0.f, 0.f};
        m[p] = 0.f; l[p] = 0.f;
    }

    for (int kv0 = 0; kv0 < S_LEN; kv0 += 64) {
        // S^T tiles: lane (rl,g) holds S[q=qbase+rl][kv = kv0 + t*16 + g*4 + jj]
        f32x4 sc[2][4];
        #pragma unroll
        for (int t = 0; t < 4; ++t) {
            #pragma unroll
            for (int p = 0; p < 2; ++p) {
                f32x4 z = (f32x4){0.f, 0.f, 0.f, 0.f};
                #pragma unroll
                for (int kc = 0; kc < 2; ++kc) {
                    bf16x8 kf = *(const bf16x8*)&Kp[(size_t)(kv0 + t * 16 + rl) * 128 + p * 64 + kc * 32 + g * 8];
                    z = __builtin_amdgcn_mfma_f32_16x16x32_bf16(kf, qf[p][kc], z, 0, 0, 0);
                }
                sc[p][t] = z * SC;
            }
        }

        // block max per q-row (lane-local 15 fmax + 2 shuffles)
        float bm[2];
        #pragma unroll
        for (int p = 0; p < 2; ++p) {
            float mx = sc[p][0][0];
            #pragma unroll
            for (int t = 0; t < 4; ++t)
                #pragma unroll
                for (int jj = 0; jj < 4; ++jj)
                    mx = fmaxf(mx, sc[p][t][jj]);
            mx = fmaxf(mx, __shfl_xor(mx, 16, 64));
            mx = fmaxf(mx, __shfl_xor(mx, 32, 64));
            bm[p] = mx;
        }

        if (kv0 == 0) {
            m[0] = bm[0]; m[1] = bm[1];
        } else if (!__all((bm[0] <= m[0] + 8.f) && (bm[1] <= m[1] + 8.f))) {
            // rare rescale path (T13)
            #pragma unroll
            for (int p = 0; p < 2; ++p) {
                float mn = fmaxf(m[p], bm[p]);
                float fac = exp2f(m[p] - mn);
                l[p] *= fac; m[p] = mn;
                #pragma unroll
                for (int jj = 0; jj < 4; ++jj) {
                    float fq = __shfl(fac, g * 4 + jj, 64);
                    #pragma unroll
                    for (int t = 0; t < 4; ++t) acc[p][t][jj] *= fq;
                }
            }
        }

        // P = exp2(S - m), packed pair writes, lane-local row sum
        #pragma unroll
        for (int p = 0; p < 2; ++p) {
            char* Pb = p ? Pb1 : Pb0;
            float rs = 0.f;
            #pragma unroll
            for (int t = 0; t < 4; ++t) {
                #pragma unroll
                for (int jjp = 0; jjp < 4; jjp += 2) {
                    float e0 = exp2f(sc[p][t][jjp]     - m[p]);
                    float e1 = exp2f(sc[p][t][jjp + 1] - m[p]);
                    rs += e0 + e1;
                    unsigned u = (unsigned)f2bf(e0) | ((unsigned)f2bf(e1) << 16);
                    *(unsigned*)(Pb + rl * 128 + (((t * 16 + g * 4 + jjp) * 2) ^ swz)) = u;
                }
            }
            rs += __shfl_xor(rs, 16, 64);
            rs += __shfl_xor(rs, 32, 64);
            l[p] += rs;
        }

        // O += P @ V   (no barrier: Pl slice is wave-private, lgkmcnt orders it)
        #pragma unroll
        for (int kc = 0; kc < 2; ++kc) {
            bf16x8 pa0 = *(const bf16x8*)(Pb0 + rl * 128 + ((kc * 64 + g * 16) ^ swz));
            bf16x8 pa1 = *(const bf16x8*)(Pb1 + rl * 128 + ((kc * 64 + g * 16) ^ swz));
            #pragma unroll
            for (int t = 0; t < 4; ++t) {
                bf16x8 vf = *(const bf16x8*)&Vp[(size_t)(t * 16 + rl) * S_LEN + kv0 + kc * 32 + g * 8];
                acc[0][t] = __builtin_amdgcn_mfma_f32_16x16x32_bf16(pa0, vf, acc[0][t], 0, 0, 0);
                acc[1][t] = __builtin_amdgcn_mfma_f32_16x16x32_bf16(pa1, vf, acc[1][t], 0, 0, 0);
            }
        }
    }

    // epilogue: redistribute l to acc layout (q = g*4+jj), combine, store
    const float lam = lam_p[0];
    float inv0[4], inv1[4];
    #pragma unroll
    for (int jj = 0; jj < 4; ++jj) {
        inv0[jj] = 1.0f / __shfl(l[0], g * 4 + jj, 64);
        inv1[jj] = lam  / __shfl(l[1], g * 4 + jj, 64);
    }
    #pragma unroll
    for (int t = 0; t < 4; ++t)
        #pragma unroll
        for (int jj = 0; jj < 4; ++jj) {
            float o = acc[0][t][jj] * inv0[jj] - acc[1][t][jj] * inv1[jj];
            int s = qbase + g * 4 + jj;
            Ocat[(size_t)s * 1024 + h * 64 + t * 16 + rl] = (short)f2bf(o);
        }
}

// ---------------- output projection GEMM ----------------
__global__ __launch_bounds__(256) void k_gemm_out(
        const short* __restrict__ Ocat, const short* __restrict__ WoT,
        const float* __restrict__ bo, float* __restrict__ Yws) {
    const int mbase = blockIdx.x * 128, nbase = blockIdx.y * 128;
    f32x4 acc[4][4];
    #pragma unroll
    for (int i = 0; i < 4; ++i)
        #pragma unroll
        for (int j = 0; j < 4; ++j)
            acc[i][j] = (f32x4){0.f, 0.f, 0.f, 0.f};

    gemm128(Ocat + (size_t)mbase * 1024, 1024, WoT + (size_t)nbase * 1024, 1024, 1024, acc);

    const int lane = threadIdx.x & 63, wave = threadIdx.x >> 6;
    const int wr = (wave >> 1) * 64, wc = (wave & 1) * 64;
    const int rl = lane & 15, g = lane >> 4;
    #pragma unroll
    for (int i = 0; i < 4; ++i)
        #pragma unroll
        for (int j = 0; j < 4; ++j)
            #pragma unroll
            for (int jj = 0; jj < 4; ++jj) {
                int s = mbase + wr + i * 16 + g * 4 + jj;
                int e = nbase + wc + j * 16 + rl;
                Yws[(size_t)s * 1024 + e] = acc[i][j][jj] + bo[e];
            }
}

// ---------------- LayerNorm + final scale ----------------
__global__ __launch_bounds__(256) void k_ln(
        const float* __restrict__ Yws, const float* __restrict__ gamma,
        const float* __restrict__ beta, float* __restrict__ out) {
    const int s = blockIdx.x;
    const int tid = threadIdx.x;
    f32x4 y = ((const f32x4*)(Yws + (size_t)s * 1024))[tid];
    float sum = y[0] + y[1] + y[2] + y[3];
    float sq  = y[0]*y[0] + y[1]*y[1] + y[2]*y[2] + y[3]*y[3];
    #pragma unroll
    for (int off = 1; off < 64; off <<= 1) {
        sum += __shfl_xor(sum, off, 64);
        sq  += __shfl_xor(sq,  off, 64);
    }
    __shared__ float ls[2][4];
    const int wave = tid >> 6, lane = tid & 63;
    if (lane == 0) { ls[0][wave] = sum; ls[1][wave] = sq; }
    __syncthreads();
    sum = ls[0][0] + ls[0][1] + ls[0][2] + ls[0][3];
    sq  = ls[1][0] + ls[1][1] + ls[1][2] + ls[1][3];
    const float mu = sum * (1.f / 1024.f);
    const float var = sq * (1.f / 1024.f) - mu * mu;
    const float rstd = rsqrtf(var + 1e-5f);
    f32x4 gg = ((const f32x4*)gamma)[tid];
    f32x4 bb = ((const f32x4*)beta)[tid];
    f32x4 o;
    #pragma unroll
    for (int k = 0; k < 4; ++k)
        o[k] = ((y[k] - mu) * rstd * gg[k] + bb[k]) * 0.2f;
    ((f32x4*)(out + (size_t)s * 1024))[tid] = o;
}

extern "C" void kernel_launch(void* const* d_in, const int* in_sizes, int n_in,
                              void* d_out, int out_size, void* d_ws, size_t ws_size,
                              hipStream_t stream) {
    const float* X     = (const float*)d_in[0];
    const float* Wq    = (const float*)d_in[1];
    const float* bq    = (const float*)d_in[2];
    const float* Wk    = (const float*)d_in[3];
    const float* bk    = (const float*)d_in[4];
    const float* Wv    = (const float*)d_in[5];
    const float* bv    = (const float*)d_in[6];
    const float* Wo    = (const float*)d_in[7];
    const float* bo    = (const float*)d_in[8];
    const float* gamma = (const float*)d_in[9];
    const float* beta  = (const float*)d_in[10];
    const float* lam   = (const float*)d_in[11];
    float* out = (float*)d_out;

    char* ws = (char*)d_ws;
    const size_t MB = 1u << 20;
    short* Xb  = (short*)(ws + 0);        // 4MB (dead after qkv gemm)
    short* WqT = (short*)(ws + 4 * MB);   // 4MB (dead after qkv gemm)
    short* WkT = (short*)(ws + 8 * MB);   // 4MB
    short* WvT = (short*)(ws + 12 * MB);  // 2MB
    short* WoT = (short*)(ws + 14 * MB);  // 2MB
    short* Qh  = (short*)(ws + 16 * MB);  // 8MB
    short* Kh  = (short*)(ws + 24 * MB);  // 8MB
    short* Vt  = (short*)(ws + 32 * MB);  // 4MB
    short* Oc  = (short*)(ws + 36 * MB);  // 4MB
    float* Yws = (float*)(ws + 0);        // 8MB, aliases Xb+WqT (both dead by then)

    k_convert_x<<<dim3(2048), dim3(256), 0, stream>>>(X, Xb, (S_LEN * EDIM) / 4);
    k_transpose_cvt<<<dim3(4, 32, 16), dim3(32, 8), 0, stream>>>(Wq, WqT, 1024, 128);
    k_transpose_cvt<<<dim3(4, 32, 16), dim3(32, 8), 0, stream>>>(Wk, WkT, 1024, 128);
    k_transpose_cvt<<<dim3(2, 32, 16), dim3(32, 8), 0, stream>>>(Wv, WvT, 1024, 64);
    k_transpose_cvt<<<dim3(32, 32, 1), dim3(32, 8), 0, stream>>>(Wo, WoT, 1024, 1024);
    k_gemm_qkv<<<dim3(16, 40), dim3(256), 0, stream>>>(Xb, WqT, WkT, WvT, bq, bk, bv, Qh, Kh, Vt);
    k_attn<<<dim3(32, 16), dim3(256), 0, stream>>>(Qh, Kh, Vt, lam, Oc);
    k_gemm_out<<<dim3(16, 8), dim3(256), 0, stream>>>(Oc, WoT, bo, Yws);
    k_ln<<<dim3(2048), dim3(256), 0, stream>>>(Yws, gamma, beta, out);
}

// Round 3
// 355.842 us; speedup vs baseline: 1.1491x; 1.0747x over previous
//
#include <hip/hip_runtime.h>

#define S_LEN 2048
#define EDIM  1024
#define HEADS 16
#define DHEAD 64

typedef __attribute__((ext_vector_type(8))) short bf16x8;
typedef __attribute__((ext_vector_type(4))) short short4v;
typedef __attribute__((ext_vector_type(4))) float f32x4;

__device__ inline unsigned short f2bf(float f) {
    unsigned int u = __float_as_uint(f);
    unsigned int r = (u + 0x7FFFu + ((u >> 16) & 1u)) >> 16;
    return (unsigned short)r;
}
__device__ inline float bf2f(unsigned short b) {
    return __uint_as_float(((unsigned int)b) << 16);
}

// ---------------- X fp32 -> bf16 ----------------
__global__ void k_convert_x(const float* __restrict__ x, short* __restrict__ xb, int n4) {
    int i = blockIdx.x * blockDim.x + threadIdx.x;
    if (i >= n4) return;
    f32x4 v = ((const f32x4*)x)[i];
    short4v o;
    o[0] = (short)f2bf(v[0]); o[1] = (short)f2bf(v[1]);
    o[2] = (short)f2bf(v[2]); o[3] = (short)f2bf(v[3]);
    ((short4v*)xb)[i] = o;
}

// ---------------- tiled transpose + fp32->bf16: in[R][C] -> out[C][R], batched over z ----------------
__global__ void k_transpose_cvt(const float* __restrict__ in, short* __restrict__ out, int R, int C) {
    __shared__ float tile[32][33];
    const int b = blockIdx.z;
    in  += (size_t)b * R * C;
    out += (size_t)b * R * C;
    const int c0 = blockIdx.x * 32, r0 = blockIdx.y * 32;
    #pragma unroll
    for (int yy = 0; yy < 4; ++yy) {
        int r = r0 + threadIdx.y + yy * 8, c = c0 + threadIdx.x;
        tile[threadIdx.y + yy * 8][threadIdx.x] = (r < R && c < C) ? in[(size_t)r * C + c] : 0.f;
    }
    __syncthreads();
    #pragma unroll
    for (int yy = 0; yy < 4; ++yy) {
        int c = c0 + threadIdx.y + yy * 8, r = r0 + threadIdx.x;
        if (c < C && r < R) out[(size_t)c * R + r] = (short)f2bf(tile[threadIdx.x][threadIdx.y + yy * 8]);
    }
}

// ---------------- 128x128 MFMA tile: A row-major [M][lda], Bt row-major [N][ldb] (k contiguous) ----------------
__device__ inline void gemm128(const short* __restrict__ A, int lda,
                               const short* __restrict__ Bt, int ldb,
                               int K, f32x4 acc[4][4]) {
    const int lane = threadIdx.x & 63;
    const int wave = threadIdx.x >> 6;
    const int wr = (wave >> 1) * 64;
    const int wc = (wave & 1) * 64;
    const int rl = lane & 15, g = lane >> 4;
    for (int k0 = 0; k0 < K; k0 += 32) {
        bf16x8 af[4], bf[4];
        #pragma unroll
        for (int f = 0; f < 4; ++f)
            af[f] = *(const bf16x8*)&A[(size_t)(wr + f * 16 + rl) * lda + k0 + g * 8];
        #pragma unroll
        for (int f = 0; f < 4; ++f)
            bf[f] = *(const bf16x8*)&Bt[(size_t)(wc + f * 16 + rl) * ldb + k0 + g * 8];
        #pragma unroll
        for (int i = 0; i < 4; ++i)
            #pragma unroll
            for (int j = 0; j < 4; ++j)
                acc[i][j] = __builtin_amdgcn_mfma_f32_16x16x32_bf16(af[i], bf[j], acc[i][j], 0, 0, 0);
    }
}

// ---------------- QKV projection GEMM ----------------
// grid.y: [0,16) Q tiles, [16,32) K tiles, [32,40) V tiles
__global__ __launch_bounds__(256) void k_gemm_qkv(
        const short* __restrict__ Xb,
        const short* __restrict__ WqT, const short* __restrict__ WkT, const short* __restrict__ WvT,
        const float* __restrict__ bq, const float* __restrict__ bk, const float* __restrict__ bv,
        short* __restrict__ Qh, short* __restrict__ Kh, short* __restrict__ Vt) {
    const int mbase = blockIdx.x * 128;
    const int y = blockIdx.y;
    const short* Bt; const float* bias; int nbase; int which;
    if (y < 16)      { which = 0; Bt = WqT; bias = bq; nbase = y * 128; }
    else if (y < 32) { which = 1; Bt = WkT; bias = bk; nbase = (y - 16) * 128; }
    else             { which = 2; Bt = WvT; bias = bv; nbase = (y - 32) * 128; }

    f32x4 acc[4][4];
    #pragma unroll
    for (int i = 0; i < 4; ++i)
        #pragma unroll
        for (int j = 0; j < 4; ++j)
            acc[i][j] = (f32x4){0.f, 0.f, 0.f, 0.f};

    gemm128(Xb + (size_t)mbase * EDIM, EDIM, Bt + (size_t)nbase * EDIM, EDIM, EDIM, acc);

    const int lane = threadIdx.x & 63, wave = threadIdx.x >> 6;
    const int wr = (wave >> 1) * 64, wc = (wave & 1) * 64;
    const int rl = lane & 15, g = lane >> 4;
    #pragma unroll
    for (int i = 0; i < 4; ++i)
        #pragma unroll
        for (int j = 0; j < 4; ++j)
            #pragma unroll
            for (int jj = 0; jj < 4; ++jj) {
                int s = mbase + wr + i * 16 + g * 4 + jj;
                int n = nbase + wc + j * 16 + rl;
                float v = acc[i][j][jj] + bias[n];
                short b16 = (short)f2bf(v);
                if (which == 0)      Qh[((size_t)(n >> 7) * S_LEN + s) * 128 + (n & 127)] = b16;
                else if (which == 1) Kh[((size_t)(n >> 7) * S_LEN + s) * 128 + (n & 127)] = b16;
                else                 Vt[(size_t)n * S_LEN + s] = b16;
            }
}

// ---------------- differential flash attention, v3: in-block KV split ----------------
// grid (S/16, H); 4 waves share 16 q rows, each wave does a strided 1/4 of KV.
// Per-wave partials (m, l, acc->bf16) exchanged through LDS (aliasing the dead
// P buffer), combined by all 256 threads at the end.
__global__ __launch_bounds__(256) void k_attn(
        const short* __restrict__ Qh, const short* __restrict__ Kh,
        const short* __restrict__ Vt, const float* __restrict__ lam_p,
        short* __restrict__ Ocat) {
    // per-wave 4KB slice: during loop = P[2][16][64] bf16; after loop = partial
    // acc exchange [2][16][64] bf16 (exact alias, same-wave in-order LDS).
    __shared__ __align__(16) char smem[4 * 4096 + 4 * 2 * 2 * 16 * 4];
    float* ML = (float*)(smem + 16384);   // [wave][p][{m,l}][16]

    const int lane = threadIdx.x & 63, wave = threadIdx.x >> 6;
    const int rl = lane & 15, g = lane >> 4;
    const int h = blockIdx.y;
    const int qbase = blockIdx.x * 16;
    const float SC = 0.125f * 1.44269504088896f;   // 1/sqrt(64) * log2(e)
    const int swz = (rl & 7) << 4;                 // XOR byte-swizzle within 128B row

    const short* Qp = Qh + (size_t)h * S_LEN * 128;
    const short* Kp = Kh + (size_t)h * S_LEN * 128;
    const short* Vp = Vt + (size_t)h * DHEAD * S_LEN;
    char* Pb0 = smem + wave * 4096;
    char* Pb1 = smem + wave * 4096 + 2048;

    bf16x8 qf[2][2];
    #pragma unroll
    for (int p = 0; p < 2; ++p)
        #pragma unroll
        for (int kc = 0; kc < 2; ++kc)
            qf[p][kc] = *(const bf16x8*)&Qp[(size_t)(qbase + rl) * 128 + p * 64 + kc * 32 + g * 8];

    f32x4 acc[2][4];
    float m[2], l[2];
    #pragma unroll
    for (int p = 0; p < 2; ++p) {
        #pragma unroll
        for (int t = 0; t < 4; ++t) acc[p][t] = (f32x4){0.f, 0.f, 0.f, 0.f};
        m[p] = 0.f; l[p] = 0.f;
    }

    int it = 0;
    for (int kv0 = wave * 64; kv0 < S_LEN; kv0 += 256, ++it) {
        // S^T tiles: lane (rl,g) holds S[q=qbase+rl][kv = kv0 + t*16 + g*4 + jj]
        f32x4 sc[2][4];
        #pragma unroll
        for (int t = 0; t < 4; ++t) {
            #pragma unroll
            for (int p = 0; p < 2; ++p) {
                f32x4 z = (f32x4){0.f, 0.f, 0.f, 0.f};
                #pragma unroll
                for (int kc = 0; kc < 2; ++kc) {
                    bf16x8 kf = *(const bf16x8*)&Kp[(size_t)(kv0 + t * 16 + rl) * 128 + p * 64 + kc * 32 + g * 8];
                    z = __builtin_amdgcn_mfma_f32_16x16x32_bf16(kf, qf[p][kc], z, 0, 0, 0);
                }
                sc[p][t] = z * SC;
            }
        }

        // block max per q-row (lane-local 15 fmax + 2 shuffles)
        float bm[2];
        #pragma unroll
        for (int p = 0; p < 2; ++p) {
            float mx = sc[p][0][0];
            #pragma unroll
            for (int t = 0; t < 4; ++t)
                #pragma unroll
                for (int jj = 0; jj < 4; ++jj)
                    mx = fmaxf(mx, sc[p][t][jj]);
            mx = fmaxf(mx, __shfl_xor(mx, 16, 64));
            mx = fmaxf(mx, __shfl_xor(mx, 32, 64));
            bm[p] = mx;
        }

        if (it == 0) {
            m[0] = bm[0]; m[1] = bm[1];
        } else if (!__all((bm[0] <= m[0] + 8.f) && (bm[1] <= m[1] + 8.f))) {
            // rare rescale path (T13)
            #pragma unroll
            for (int p = 0; p < 2; ++p) {
                float mn = fmaxf(m[p], bm[p]);
                float fac = exp2f(m[p] - mn);
                l[p] *= fac; m[p] = mn;
                #pragma unroll
                for (int jj = 0; jj < 4; ++jj) {
                    float fq = __shfl(fac, g * 4 + jj, 64);
                    #pragma unroll
                    for (int t = 0; t < 4; ++t) acc[p][t][jj] *= fq;
                }
            }
        }

        // P = exp2(S - m), packed pair writes, lane-local row sum
        #pragma unroll
        for (int p = 0; p < 2; ++p) {
            char* Pb = p ? Pb1 : Pb0;
            float rs = 0.f;
            #pragma unroll
            for (int t = 0; t < 4; ++t) {
                #pragma unroll
                for (int jjp = 0; jjp < 4; jjp += 2) {
                    float e0 = exp2f(sc[p][t][jjp]     - m[p]);
                    float e1 = exp2f(sc[p][t][jjp + 1] - m[p]);
                    rs += e0 + e1;
                    unsigned u = (unsigned)f2bf(e0) | ((unsigned)f2bf(e1) << 16);
                    *(unsigned*)(Pb + rl * 128 + (((t * 16 + g * 4 + jjp) * 2) ^ swz)) = u;
                }
            }
            rs += __shfl_xor(rs, 16, 64);
            rs += __shfl_xor(rs, 32, 64);
            l[p] += rs;
        }

        // O += P @ V   (no barrier: Pl slice is wave-private, lgkmcnt orders it)
        #pragma unroll
        for (int kc = 0; kc < 2; ++kc) {
            bf16x8 pa0 = *(const bf16x8*)(Pb0 + rl * 128 + ((kc * 64 + g * 16) ^ swz));
            bf16x8 pa1 = *(const bf16x8*)(Pb1 + rl * 128 + ((kc * 64 + g * 16) ^ swz));
            #pragma unroll
            for (int t = 0; t < 4; ++t) {
                bf16x8 vf = *(const bf16x8*)&Vp[(size_t)(t * 16 + rl) * S_LEN + kv0 + kc * 32 + g * 8];
                acc[0][t] = __builtin_amdgcn_mfma_f32_16x16x32_bf16(pa0, vf, acc[0][t], 0, 0, 0);
                acc[1][t] = __builtin_amdgcn_mfma_f32_16x16x32_bf16(pa1, vf, acc[1][t], 0, 0, 0);
            }
        }
    }

    // ---- exchange partials: acc (bf16) into own P slice, m/l into ML ----
    {
        unsigned short* Xw = (unsigned short*)(smem + wave * 4096);
        #pragma unroll
        for (int p = 0; p < 2; ++p) {
            #pragma unroll
            for (int t = 0; t < 4; ++t)
                #pragma unroll
                for (int jj = 0; jj < 4; ++jj)
                    Xw[p * 1024 + (g * 4 + jj) * 64 + t * 16 + rl] = f2bf(acc[p][t][jj]);
            if (g == 0) {
                ML[(wave * 2 + p) * 32 + rl]      = m[p];
                ML[(wave * 2 + p) * 32 + 16 + rl] = l[p];
            }
        }
    }
    __syncthreads();

    // ---- combine 4 KV-split partials; thread t -> q = t>>4, d0 = (t&15)*4 ----
    {
        const int q = threadIdx.x >> 4, d0 = (threadIdx.x & 15) * 4;
        const float lam = lam_p[0];
        float res[2][4];
        float invL[2];
        #pragma unroll
        for (int p = 0; p < 2; ++p) {
            float mmax = ML[(0 * 2 + p) * 32 + q];
            #pragma unroll
            for (int w = 1; w < 4; ++w)
                mmax = fmaxf(mmax, ML[(w * 2 + p) * 32 + q]);
            float L = 0.f;
            float o0 = 0.f, o1 = 0.f, o2 = 0.f, o3 = 0.f;
            #pragma unroll
            for (int w = 0; w < 4; ++w) {
                float f = exp2f(ML[(w * 2 + p) * 32 + q] - mmax);
                L += f * ML[(w * 2 + p) * 32 + 16 + q];
                const unsigned short* xv =
                    (const unsigned short*)(smem + w * 4096 + p * 2048 + q * 128 + d0 * 2);
                o0 += f * bf2f(xv[0]);
                o1 += f * bf2f(xv[1]);
                o2 += f * bf2f(xv[2]);
                o3 += f * bf2f(xv[3]);
            }
            res[p][0] = o0; res[p][1] = o1; res[p][2] = o2; res[p][3] = o3;
            invL[p] = 1.0f / L;
        }
        short4v ov;
        #pragma unroll
        for (int k = 0; k < 4; ++k)
            ov[k] = (short)f2bf(res[0][k] * invL[0] - lam * res[1][k] * invL[1]);
        *(short4v*)&Ocat[(size_t)(qbase + q) * 1024 + h * 64 + d0] = ov;
    }
}

// ---------------- output projection GEMM ----------------
__global__ __launch_bounds__(256) void k_gemm_out(
        const short* __restrict__ Ocat, const short* __restrict__ WoT,
        const float* __restrict__ bo, float* __restrict__ Yws) {
    const int mbase = blockIdx.x * 128, nbase = blockIdx.y * 128;
    f32x4 acc[4][4];
    #pragma unroll
    for (int i = 0; i < 4; ++i)
        #pragma unroll
        for (int j = 0; j < 4; ++j)
            acc[i][j] = (f32x4){0.f, 0.f, 0.f, 0.f};

    gemm128(Ocat + (size_t)mbase * 1024, 1024, WoT + (size_t)nbase * 1024, 1024, 1024, acc);

    const int lane = threadIdx.x & 63, wave = threadIdx.x >> 6;
    const int wr = (wave >> 1) * 64, wc = (wave & 1) * 64;
    const int rl = lane & 15, g = lane >> 4;
    #pragma unroll
    for (int i = 0; i < 4; ++i)
        #pragma unroll
        for (int j = 0; j < 4; ++j)
            #pragma unroll
            for (int jj = 0; jj < 4; ++jj) {
                int s = mbase + wr + i * 16 + g * 4 + jj;
                int e = nbase + wc + j * 16 + rl;
                Yws[(size_t)s * 1024 + e] = acc[i][j][jj] + bo[e];
            }
}

// ---------------- LayerNorm + final scale ----------------
__global__ __launch_bounds__(256) void k_ln(
        const float* __restrict__ Yws, const float* __restrict__ gamma,
        const float* __restrict__ beta, float* __restrict__ out) {
    const int s = blockIdx.x;
    const int tid = threadIdx.x;
    f32x4 y = ((const f32x4*)(Yws + (size_t)s * 1024))[tid];
    float sum = y[0] + y[1] + y[2] + y[3];
    float sq  = y[0]*y[0] + y[1]*y[1] + y[2]*y[2] + y[3]*y[3];
    #pragma unroll
    for (int off = 1; off < 64; off <<= 1) {
        sum += __shfl_xor(sum, off, 64);
        sq  += __shfl_xor(sq,  off, 64);
    }
    __shared__ float ls[2][4];
    const int wave = tid >> 6, lane = tid & 63;
    if (lane == 0) { ls[0][wave] = sum; ls[1][wave] = sq; }
    __syncthreads();
    sum = ls[0][0] + ls[0][1] + ls[0][2] + ls[0][3];
    sq  = ls[1][0] + ls[1][1] + ls[1][2] + ls[1][3];
    const float mu = sum * (1.f / 1024.f);
    const float var = sq * (1.f / 1024.f) - mu * mu;
    const float rstd = rsqrtf(var + 1e-5f);
    f32x4 gg = ((const f32x4*)gamma)[tid];
    f32x4 bb = ((const f32x4*)beta)[tid];
    f32x4 o;
    #pragma unroll
    for (int k = 0; k < 4; ++k)
        o[k] = ((y[k] - mu) * rstd * gg[k] + bb[k]) * 0.2f;
    ((f32x4*)(out + (size_t)s * 1024))[tid] = o;
}

extern "C" void kernel_launch(void* const* d_in, const int* in_sizes, int n_in,
                              void* d_out, int out_size, void* d_ws, size_t ws_size,
                              hipStream_t stream) {
    const float* X     = (const float*)d_in[0];
    const float* Wq    = (const float*)d_in[1];
    const float* bq    = (const float*)d_in[2];
    const float* Wk    = (const float*)d_in[3];
    const float* bk    = (const float*)d_in[4];
    const float* Wv    = (const float*)d_in[5];
    const float* bv    = (const float*)d_in[6];
    const float* Wo    = (const float*)d_in[7];
    const float* bo    = (const float*)d_in[8];
    const float* gamma = (const float*)d_in[9];
    const float* beta  = (const float*)d_in[10];
    const float* lam   = (const float*)d_in[11];
    float* out = (float*)d_out;

    char* ws = (char*)d_ws;
    const size_t MB = 1u << 20;
    short* Xb  = (short*)(ws + 0);        // 4MB (dead after qkv gemm)
    short* WqT = (short*)(ws + 4 * MB);   // 4MB (dead after qkv gemm)
    short* WkT = (short*)(ws + 8 * MB);   // 4MB
    short* WvT = (short*)(ws + 12 * MB);  // 2MB
    short* WoT = (short*)(ws + 14 * MB);  // 2MB
    short* Qh  = (short*)(ws + 16 * MB);  // 8MB
    short* Kh  = (short*)(ws + 24 * MB);  // 8MB
    short* Vt  = (short*)(ws + 32 * MB);  // 4MB
    short* Oc  = (short*)(ws + 36 * MB);  // 4MB
    float* Yws = (float*)(ws + 0);        // 8MB, aliases Xb+WqT (both dead by then)

    k_convert_x<<<dim3(2048), dim3(256), 0, stream>>>(X, Xb, (S_LEN * EDIM) / 4);
    k_transpose_cvt<<<dim3(4, 32, 16), dim3(32, 8), 0, stream>>>(Wq, WqT, 1024, 128);
    k_transpose_cvt<<<dim3(4, 32, 16), dim3(32, 8), 0, stream>>>(Wk, WkT, 1024, 128);
    k_transpose_cvt<<<dim3(2, 32, 16), dim3(32, 8), 0, stream>>>(Wv, WvT, 1024, 64);
    k_transpose_cvt<<<dim3(32, 32, 1), dim3(32, 8), 0, stream>>>(Wo, WoT, 1024, 1024);
    k_gemm_qkv<<<dim3(16, 40), dim3(256), 0, stream>>>(Xb, WqT, WkT, WvT, bq, bk, bv, Qh, Kh, Vt);
    k_attn<<<dim3(128, 16), dim3(256), 0, stream>>>(Qh, Kh, Vt, lam, Oc);
    k_gemm_out<<<dim3(16, 8), dim3(256), 0, stream>>>(Oc, WoT, bo, Yws);
    k_ln<<<dim3(2048), dim3(256), 0, stream>>>(Yws, gamma, beta, out);
}

// Round 4
// 250.944 us; speedup vs baseline: 1.6294x; 1.4180x over previous
//
#include <hip/hip_runtime.h>

#define S_LEN 2048
#define EDIM  1024
#define HEADS 16
#define DHEAD 64

typedef __attribute__((ext_vector_type(8))) short bf16x8;
typedef __attribute__((ext_vector_type(4))) short short4v;
typedef __attribute__((ext_vector_type(4))) float f32x4;

__device__ inline unsigned short f2bf(float f) {
    unsigned int u = __float_as_uint(f);
    unsigned int r = (u + 0x7FFFu + ((u >> 16) & 1u)) >> 16;
    return (unsigned short)r;
}
__device__ inline float bf2f(unsigned short b) {
    return __uint_as_float(((unsigned int)b) << 16);
}
__device__ inline void load_lds16(const void* g, void* l) {
    __builtin_amdgcn_global_load_lds(
        (const __attribute__((address_space(1))) unsigned int*)g,
        (__attribute__((address_space(3))) unsigned int*)l, 16, 0, 0);
}

// ---------------- X fp32 -> bf16 ----------------
__global__ void k_convert_x(const float* __restrict__ x, short* __restrict__ xb, int n4) {
    int i = blockIdx.x * blockDim.x + threadIdx.x;
    if (i >= n4) return;
    f32x4 v = ((const f32x4*)x)[i];
    short4v o;
    o[0] = (short)f2bf(v[0]); o[1] = (short)f2bf(v[1]);
    o[2] = (short)f2bf(v[2]); o[3] = (short)f2bf(v[3]);
    ((short4v*)xb)[i] = o;
}

// ---------------- tiled transpose + fp32->bf16: in[R][C] -> out[C][R], batched over z ----------------
__global__ void k_transpose_cvt(const float* __restrict__ in, short* __restrict__ out, int R, int C) {
    __shared__ float tile[32][33];
    const int b = blockIdx.z;
    in  += (size_t)b * R * C;
    out += (size_t)b * R * C;
    const int c0 = blockIdx.x * 32, r0 = blockIdx.y * 32;
    #pragma unroll
    for (int yy = 0; yy < 4; ++yy) {
        int r = r0 + threadIdx.y + yy * 8, c = c0 + threadIdx.x;
        tile[threadIdx.y + yy * 8][threadIdx.x] = (r < R && c < C) ? in[(size_t)r * C + c] : 0.f;
    }
    __syncthreads();
    #pragma unroll
    for (int yy = 0; yy < 4; ++yy) {
        int c = c0 + threadIdx.y + yy * 8, r = r0 + threadIdx.x;
        if (c < C && r < R) out[(size_t)c * R + r] = (short)f2bf(tile[threadIdx.x][threadIdx.y + yy * 8]);
    }
}

// ---------------- 128x128 MFMA tile: A row-major [M][lda], Bt row-major [N][ldb] (k contiguous) ----------------
__device__ inline void gemm128(const short* __restrict__ A, int lda,
                               const short* __restrict__ Bt, int ldb,
                               int K, f32x4 acc[4][4]) {
    const int lane = threadIdx.x & 63;
    const int wave = threadIdx.x >> 6;
    const int wr = (wave >> 1) * 64;
    const int wc = (wave & 1) * 64;
    const int rl = lane & 15, g = lane >> 4;
    for (int k0 = 0; k0 < K; k0 += 32) {
        bf16x8 af[4], bf[4];
        #pragma unroll
        for (int f = 0; f < 4; ++f)
            af[f] = *(const bf16x8*)&A[(size_t)(wr + f * 16 + rl) * lda + k0 + g * 8];
        #pragma unroll
        for (int f = 0; f < 4; ++f)
            bf[f] = *(const bf16x8*)&Bt[(size_t)(wc + f * 16 + rl) * ldb + k0 + g * 8];
        #pragma unroll
        for (int i = 0; i < 4; ++i)
            #pragma unroll
            for (int j = 0; j < 4; ++j)
                acc[i][j] = __builtin_amdgcn_mfma_f32_16x16x32_bf16(af[i], bf[j], acc[i][j], 0, 0, 0);
    }
}

// ---------------- QKV projection GEMM ----------------
// grid.y: [0,16) Q tiles, [16,32) K tiles, [32,40) V tiles
// Q is pre-scaled by 1/sqrt(d)*log2(e) so attention scores come out in exp2 domain.
__global__ __launch_bounds__(256) void k_gemm_qkv(
        const short* __restrict__ Xb,
        const short* __restrict__ WqT, const short* __restrict__ WkT, const short* __restrict__ WvT,
        const float* __restrict__ bq, const float* __restrict__ bk, const float* __restrict__ bv,
        short* __restrict__ Qh, short* __restrict__ Kh, short* __restrict__ Vt) {
    const int mbase = blockIdx.x * 128;
    const int y = blockIdx.y;
    const short* Bt; const float* bias; int nbase; int which;
    if (y < 16)      { which = 0; Bt = WqT; bias = bq; nbase = y * 128; }
    else if (y < 32) { which = 1; Bt = WkT; bias = bk; nbase = (y - 16) * 128; }
    else             { which = 2; Bt = WvT; bias = bv; nbase = (y - 32) * 128; }

    f32x4 acc[4][4];
    #pragma unroll
    for (int i = 0; i < 4; ++i)
        #pragma unroll
        for (int j = 0; j < 4; ++j)
            acc[i][j] = (f32x4){0.f, 0.f, 0.f, 0.f};

    gemm128(Xb + (size_t)mbase * EDIM, EDIM, Bt + (size_t)nbase * EDIM, EDIM, EDIM, acc);

    const int lane = threadIdx.x & 63, wave = threadIdx.x >> 6;
    const int wr = (wave >> 1) * 64, wc = (wave & 1) * 64;
    const int rl = lane & 15, g = lane >> 4;
    const float qscale = 0.125f * 1.44269504088896f;
    #pragma unroll
    for (int i = 0; i < 4; ++i)
        #pragma unroll
        for (int j = 0; j < 4; ++j)
            #pragma unroll
            for (int jj = 0; jj < 4; ++jj) {
                int s = mbase + wr + i * 16 + g * 4 + jj;
                int n = nbase + wc + j * 16 + rl;
                float v = acc[i][j][jj] + bias[n];
                if (which == 0) v *= qscale;
                short b16 = (short)f2bf(v);
                if (which == 0)      Qh[((size_t)(n >> 7) * S_LEN + s) * 128 + (n & 127)] = b16;
                else if (which == 1) Kh[((size_t)(n >> 7) * S_LEN + s) * 128 + (n & 127)] = b16;
                else                 Vt[(size_t)n * S_LEN + s] = b16;
            }
}

// ---------------- differential flash attention, v4: LDS-staged shared KV ----------------
// grid (S/64, H); 4 waves own different 16 q-rows of a 64-row q tile; the 64-row
// KV tile (K 16KB + V 8KB) is staged once per block into double-buffered LDS via
// global_load_lds (linear dest, inverse-swizzled per-lane global source; reads
// XOR the same swizzle -> 2-way-max bank conflicts).
__global__ __launch_bounds__(256) void k_attn(
        const short* __restrict__ Qh, const short* __restrict__ Kh,
        const short* __restrict__ Vt, const float* __restrict__ lam_p,
        short* __restrict__ Ocat) {
    __shared__ __align__(16) char smem[65536];
    char* Kl = smem;            // 2 x 16KB  K tiles [64][128] bf16, row-swizzled
    char* Vl = smem + 32768;    // 2 x 8KB   V tiles [64 d][64 kv] bf16, row-swizzled
    char* Pl = smem + 49152;    // 4 waves x 4KB P buffers [2][16][64] bf16, swizzled

    const int lane = threadIdx.x & 63, wave = threadIdx.x >> 6;
    const int rl = lane & 15, g = lane >> 4;
    const int h = blockIdx.y;
    const int qbase = blockIdx.x * 64 + wave * 16;
    const int swz = (rl & 7) << 4;
    const int kx = rl & 7;

    const char* Kgb = (const char*)(Kh + (size_t)h * S_LEN * 128);
    const char* Vgb = (const char*)(Vt + (size_t)h * DHEAD * S_LEN);
    const short* Qp = Qh + (size_t)h * S_LEN * 128;
    char* Pb0 = Pl + wave * 4096;
    char* Pb1 = Pb0 + 2048;

    // precomputed per-lane staging offsets (inverse swizzle on the global source)
    const int kofs0 = (lane >> 4) * 256 + (((lane & 15) ^ (lane >> 4)) << 4);
    const int kofs1 = (lane >> 4) * 256 + (((lane & 15) ^ ((lane >> 4) + 4)) << 4);
    const int vofs  = (lane >> 3) * 4096 + (((lane & 7) ^ (lane >> 3)) << 4);

    bf16x8 qf[2][2];
    #pragma unroll
    for (int p = 0; p < 2; ++p)
        #pragma unroll
        for (int kc = 0; kc < 2; ++kc)
            qf[p][kc] = *(const bf16x8*)&Qp[(size_t)(qbase + rl) * 128 + p * 64 + kc * 32 + g * 8];

    // prologue: stage tile 0 into buffer 0
    #pragma unroll
    for (int cc = 0; cc < 4; ++cc) {
        int c = wave * 4 + cc;
        load_lds16(Kgb + c * 1024 + ((cc & 1) ? kofs1 : kofs0), Kl + c * 1024);
    }
    #pragma unroll
    for (int cc = 0; cc < 2; ++cc) {
        int c = wave * 2 + cc;
        load_lds16(Vgb + (size_t)c * 32768 + vofs, Vl + c * 1024);
    }

    f32x4 acc[2][4];
    float m[2], l[2];
    #pragma unroll
    for (int p = 0; p < 2; ++p) {
        #pragma unroll
        for (int t = 0; t < 4; ++t) acc[p][t] = (f32x4){0.f, 0.f, 0.f, 0.f};
        m[p] = 0.f; l[p] = 0.f;
    }

    __syncthreads();

    const int NIT = S_LEN / 64;
    for (int it = 0; it < NIT; ++it) {
        const int cur = it & 1;
        // ---- stage next tile into the other buffer (overlaps with compute) ----
        if (it + 1 < NIT) {
            const size_t nkv = (size_t)(it + 1) * 64;
            char* kb = Kl + (cur ^ 1) * 16384;
            char* vb = Vl + (cur ^ 1) * 8192;
            #pragma unroll
            for (int cc = 0; cc < 4; ++cc) {
                int c = wave * 4 + cc;
                load_lds16(Kgb + nkv * 256 + c * 1024 + ((cc & 1) ? kofs1 : kofs0), kb + c * 1024);
            }
            #pragma unroll
            for (int cc = 0; cc < 2; ++cc) {
                int c = wave * 2 + cc;
                load_lds16(Vgb + (size_t)c * 32768 + nkv * 2 + vofs, vb + c * 1024);
            }
        }
        const char* kb = Kl + cur * 16384;
        const char* vb = Vl + cur * 8192;

        // ---- QK^T (swapped: mfma(K,Q)), scores already in exp2 domain ----
        f32x4 sc[2][4];
        #pragma unroll
        for (int t = 0; t < 4; ++t) {
            #pragma unroll
            for (int p = 0; p < 2; ++p) {
                f32x4 z = (f32x4){0.f, 0.f, 0.f, 0.f};
                #pragma unroll
                for (int kc = 0; kc < 2; ++kc) {
                    bf16x8 kf = *(const bf16x8*)(kb + t * 4096 + rl * 256 + (((p * 8 + kc * 4 + g) ^ kx) << 4));
                    z = __builtin_amdgcn_mfma_f32_16x16x32_bf16(kf, qf[p][kc], z, 0, 0, 0);
                }
                sc[p][t] = z;
            }
        }

        // ---- block max per q-row ----
        float bm[2];
        #pragma unroll
        for (int p = 0; p < 2; ++p) {
            float mx = sc[p][0][0];
            #pragma unroll
            for (int t = 0; t < 4; ++t)
                #pragma unroll
                for (int jj = 0; jj < 4; ++jj)
                    mx = fmaxf(mx, sc[p][t][jj]);
            mx = fmaxf(mx, __shfl_xor(mx, 16, 64));
            mx = fmaxf(mx, __shfl_xor(mx, 32, 64));
            bm[p] = mx;
        }

        if (it == 0) {
            m[0] = bm[0]; m[1] = bm[1];
        } else if (!__all((bm[0] <= m[0] + 8.f) && (bm[1] <= m[1] + 8.f))) {
            #pragma unroll
            for (int p = 0; p < 2; ++p) {
                float mn = fmaxf(m[p], bm[p]);
                float fac = exp2f(m[p] - mn);
                l[p] *= fac; m[p] = mn;
                #pragma unroll
                for (int jj = 0; jj < 4; ++jj) {
                    float fq = __shfl(fac, g * 4 + jj, 64);
                    #pragma unroll
                    for (int t = 0; t < 4; ++t) acc[p][t][jj] *= fq;
                }
            }
        }

        // ---- P = exp2(S - m): packed v_cvt_pk_bf16_f32 writes + lane-local sum ----
        #pragma unroll
        for (int p = 0; p < 2; ++p) {
            char* Pb = p ? Pb1 : Pb0;
            float rs = 0.f;
            #pragma unroll
            for (int t = 0; t < 4; ++t) {
                #pragma unroll
                for (int jjp = 0; jjp < 4; jjp += 2) {
                    float e0 = exp2f(sc[p][t][jjp]     - m[p]);
                    float e1 = exp2f(sc[p][t][jjp + 1] - m[p]);
                    rs += e0 + e1;
                    unsigned u;
                    asm("v_cvt_pk_bf16_f32 %0, %1, %2" : "=v"(u) : "v"(e0), "v"(e1));
                    *(unsigned*)(Pb + rl * 128 + (((t * 16 + g * 4 + jjp) * 2) ^ swz)) = u;
                }
            }
            rs += __shfl_xor(rs, 16, 64);
            rs += __shfl_xor(rs, 32, 64);
            l[p] += rs;
        }

        // ---- O += P @ V (P via wave-private LDS; V from staged tile) ----
        #pragma unroll
        for (int kc = 0; kc < 2; ++kc) {
            bf16x8 pa0 = *(const bf16x8*)(Pb0 + rl * 128 + ((kc * 64 + g * 16) ^ swz));
            bf16x8 pa1 = *(const bf16x8*)(Pb1 + rl * 128 + ((kc * 64 + g * 16) ^ swz));
            #pragma unroll
            for (int t = 0; t < 4; ++t) {
                bf16x8 vf = *(const bf16x8*)(vb + t * 2048 + rl * 128 + (((kc * 4 + g) ^ kx) << 4));
                acc[0][t] = __builtin_amdgcn_mfma_f32_16x16x32_bf16(pa0, vf, acc[0][t], 0, 0, 0);
                acc[1][t] = __builtin_amdgcn_mfma_f32_16x16x32_bf16(pa1, vf, acc[1][t], 0, 0, 0);
            }
        }
        __syncthreads();
    }

    // ---- epilogue: redistribute l to acc layout (q = g*4+jj), combine, store ----
    const float lam = lam_p[0];
    float inv0[4], inv1[4];
    #pragma unroll
    for (int jj = 0; jj < 4; ++jj) {
        inv0[jj] = 1.0f / __shfl(l[0], g * 4 + jj, 64);
        inv1[jj] = lam  / __shfl(l[1], g * 4 + jj, 64);
    }
    #pragma unroll
    for (int t = 0; t < 4; ++t)
        #pragma unroll
        for (int jj = 0; jj < 4; ++jj) {
            float o = acc[0][t][jj] * inv0[jj] - acc[1][t][jj] * inv1[jj];
            int s = qbase + g * 4 + jj;
            Ocat[(size_t)s * 1024 + h * 64 + t * 16 + rl] = (short)f2bf(o);
        }
}

// ---------------- output projection GEMM ----------------
__global__ __launch_bounds__(256) void k_gemm_out(
        const short* __restrict__ Ocat, const short* __restrict__ WoT,
        const float* __restrict__ bo, float* __restrict__ Yws) {
    const int mbase = blockIdx.x * 128, nbase = blockIdx.y * 128;
    f32x4 acc[4][4];
    #pragma unroll
    for (int i = 0; i < 4; ++i)
        #pragma unroll
        for (int j = 0; j < 4; ++j)
            acc[i][j] = (f32x4){0.f, 0.f, 0.f, 0.f};

    gemm128(Ocat + (size_t)mbase * 1024, 1024, WoT + (size_t)nbase * 1024, 1024, 1024, acc);

    const int lane = threadIdx.x & 63, wave = threadIdx.x >> 6;
    const int wr = (wave >> 1) * 64, wc = (wave & 1) * 64;
    const int rl = lane & 15, g = lane >> 4;
    #pragma unroll
    for (int i = 0; i < 4; ++i)
        #pragma unroll
        for (int j = 0; j < 4; ++j)
            #pragma unroll
            for (int jj = 0; jj < 4; ++jj) {
                int s = mbase + wr + i * 16 + g * 4 + jj;
                int e = nbase + wc + j * 16 + rl;
                Yws[(size_t)s * 1024 + e] = acc[i][j][jj] + bo[e];
            }
}

// ---------------- LayerNorm + final scale ----------------
__global__ __launch_bounds__(256) void k_ln(
        const float* __restrict__ Yws, const float* __restrict__ gamma,
        const float* __restrict__ beta, float* __restrict__ out) {
    const int s = blockIdx.x;
    const int tid = threadIdx.x;
    f32x4 y = ((const f32x4*)(Yws + (size_t)s * 1024))[tid];
    float sum = y[0] + y[1] + y[2] + y[3];
    float sq  = y[0]*y[0] + y[1]*y[1] + y[2]*y[2] + y[3]*y[3];
    #pragma unroll
    for (int off = 1; off < 64; off <<= 1) {
        sum += __shfl_xor(sum, off, 64);
        sq  += __shfl_xor(sq,  off, 64);
    }
    __shared__ float ls[2][4];
    const int wave = tid >> 6, lane = tid & 63;
    if (lane == 0) { ls[0][wave] = sum; ls[1][wave] = sq; }
    __syncthreads();
    sum = ls[0][0] + ls[0][1] + ls[0][2] + ls[0][3];
    sq  = ls[1][0] + ls[1][1] + ls[1][2] + ls[1][3];
    const float mu = sum * (1.f / 1024.f);
    const float var = sq * (1.f / 1024.f) - mu * mu;
    const float rstd = rsqrtf(var + 1e-5f);
    f32x4 gg = ((const f32x4*)gamma)[tid];
    f32x4 bb = ((const f32x4*)beta)[tid];
    f32x4 o;
    #pragma unroll
    for (int k = 0; k < 4; ++k)
        o[k] = ((y[k] - mu) * rstd * gg[k] + bb[k]) * 0.2f;
    ((f32x4*)(out + (size_t)s * 1024))[tid] = o;
}

extern "C" void kernel_launch(void* const* d_in, const int* in_sizes, int n_in,
                              void* d_out, int out_size, void* d_ws, size_t ws_size,
                              hipStream_t stream) {
    const float* X     = (const float*)d_in[0];
    const float* Wq    = (const float*)d_in[1];
    const float* bq    = (const float*)d_in[2];
    const float* Wk    = (const float*)d_in[3];
    const float* bk    = (const float*)d_in[4];
    const float* Wv    = (const float*)d_in[5];
    const float* bv    = (const float*)d_in[6];
    const float* Wo    = (const float*)d_in[7];
    const float* bo    = (const float*)d_in[8];
    const float* gamma = (const float*)d_in[9];
    const float* beta  = (const float*)d_in[10];
    const float* lam   = (const float*)d_in[11];
    float* out = (float*)d_out;

    char* ws = (char*)d_ws;
    const size_t MB = 1u << 20;
    short* Xb  = (short*)(ws + 0);        // 4MB (dead after qkv gemm)
    short* WqT = (short*)(ws + 4 * MB);   // 4MB (dead after qkv gemm)
    short* WkT = (short*)(ws + 8 * MB);   // 4MB
    short* WvT = (short*)(ws + 12 * MB);  // 2MB
    short* WoT = (short*)(ws + 14 * MB);  // 2MB
    short* Qh  = (short*)(ws + 16 * MB);  // 8MB
    short* Kh  = (short*)(ws + 24 * MB);  // 8MB
    short* Vt  = (short*)(ws + 32 * MB);  // 4MB
    short* Oc  = (short*)(ws + 36 * MB);  // 4MB
    float* Yws = (float*)(ws + 0);        // 8MB, aliases Xb+WqT (both dead by then)

    k_convert_x<<<dim3(2048), dim3(256), 0, stream>>>(X, Xb, (S_LEN * EDIM) / 4);
    k_transpose_cvt<<<dim3(4, 32, 16), dim3(32, 8), 0, stream>>>(Wq, WqT, 1024, 128);
    k_transpose_cvt<<<dim3(4, 32, 16), dim3(32, 8), 0, stream>>>(Wk, WkT, 1024, 128);
    k_transpose_cvt<<<dim3(2, 32, 16), dim3(32, 8), 0, stream>>>(Wv, WvT, 1024, 64);
    k_transpose_cvt<<<dim3(32, 32, 1), dim3(32, 8), 0, stream>>>(Wo, WoT, 1024, 1024);
    k_gemm_qkv<<<dim3(16, 40), dim3(256), 0, stream>>>(Xb, WqT, WkT, WvT, bq, bk, bv, Qh, Kh, Vt);
    k_attn<<<dim3(32, 16), dim3(256), 0, stream>>>(Qh, Kh, Vt, lam, Oc);
    k_gemm_out<<<dim3(16, 8), dim3(256), 0, stream>>>(Oc, WoT, bo, Yws);
    k_ln<<<dim3(2048), dim3(256), 0, stream>>>(Yws, gamma, beta, out);
}

// Round 5
// 178.076 us; speedup vs baseline: 2.2961x; 1.4092x over previous
//
#include <hip/hip_runtime.h>

#define S_LEN 2048
#define EDIM  1024
#define HEADS 16
#define DHEAD 64

typedef __attribute__((ext_vector_type(8))) short bf16x8;
typedef __attribute__((ext_vector_type(4))) short short4v;
typedef __attribute__((ext_vector_type(4))) float f32x4;

__device__ inline unsigned short f2bf(float f) {
    unsigned int u = __float_as_uint(f);
    unsigned int r = (u + 0x7FFFu + ((u >> 16) & 1u)) >> 16;
    return (unsigned short)r;
}
__device__ inline float bf2f(unsigned short b) {
    return __uint_as_float(((unsigned int)b) << 16);
}
__device__ inline void load_lds16(const void* g, void* l) {
    __builtin_amdgcn_global_load_lds(
        (const __attribute__((address_space(1))) unsigned int*)g,
        (__attribute__((address_space(3))) unsigned int*)l, 16, 0, 0);
}

// ---------------- X fp32 -> bf16 ----------------
__global__ void k_convert_x(const float* __restrict__ x, short* __restrict__ xb, int n4) {
    int i = blockIdx.x * blockDim.x + threadIdx.x;
    if (i >= n4) return;
    f32x4 v = ((const f32x4*)x)[i];
    short4v o;
    o[0] = (short)f2bf(v[0]); o[1] = (short)f2bf(v[1]);
    o[2] = (short)f2bf(v[2]); o[3] = (short)f2bf(v[3]);
    ((short4v*)xb)[i] = o;
}

// ---------------- tiled transpose + fp32->bf16: in[R][C] -> out[C][R], batched over z ----------------
__global__ void k_transpose_cvt(const float* __restrict__ in, short* __restrict__ out, int R, int C) {
    __shared__ float tile[32][33];
    const int b = blockIdx.z;
    in  += (size_t)b * R * C;
    out += (size_t)b * R * C;
    const int c0 = blockIdx.x * 32, r0 = blockIdx.y * 32;
    #pragma unroll
    for (int yy = 0; yy < 4; ++yy) {
        int r = r0 + threadIdx.y + yy * 8, c = c0 + threadIdx.x;
        tile[threadIdx.y + yy * 8][threadIdx.x] = (r < R && c < C) ? in[(size_t)r * C + c] : 0.f;
    }
    __syncthreads();
    #pragma unroll
    for (int yy = 0; yy < 4; ++yy) {
        int c = c0 + threadIdx.y + yy * 8, r = r0 + threadIdx.x;
        if (c < C && r < R) out[(size_t)c * R + r] = (short)f2bf(tile[threadIdx.x][threadIdx.y + yy * 8]);
    }
}

// ---------------- LDS-staged MFMA GEMM core (m97 structure) ----------------
// A row-major [M][K] bf16, Bt row-major [N][K] bf16 (both k-contiguous).
// BK=64 (128B rows in LDS), single-buffered, 2 barriers per K-step.
// Both-sides XOR swizzle: linear LDS dest (global_load_lds requirement),
// inverse-swizzled per-lane GLOBAL source, XOR on ds_read -> 2-way max.
template<int BM, int BN, int WR, int WC>
__device__ inline void gemm_core(const char* Ag, int ldaB, const char* Bg, int ldbB,
                                 int K, char* sA, char* sB, f32x4* acc) {
    constexpr int FM = BM / (WR * 16), FN = BN / (WC * 16);
    constexpr int RA = BM / 32, RB = BN / 32;
    const int lane = threadIdx.x & 63, wave = threadIdx.x >> 6;
    const int rl = lane & 15, g = lane >> 4;
    const int wrow = (wave / WC) * (BM / WR);
    const int wcol = (wave % WC) * (BN / WC);
    const int lr = lane >> 3;                 // row within 8-row staging group
    const int lc = ((lane & 7) ^ lr) << 4;    // inverse-swizzled 16B chunk
    const char* aSrc = Ag + (size_t)(wave * 8 + lr) * ldaB + lc;
    const char* bSrc = Bg + (size_t)(wave * 8 + lr) * ldbB + lc;

    for (int t = 0; t < K / 64; ++t) {
        __syncthreads();   // prev compute's ds_reads drained (lgkmcnt before barrier)
        #pragma unroll
        for (int i = 0; i < RA; ++i)
            load_lds16(aSrc + (size_t)t * 128 + (size_t)i * 32 * ldaB, sA + (i * 4 + wave) * 1024);
        #pragma unroll
        for (int i = 0; i < RB; ++i)
            load_lds16(bSrc + (size_t)t * 128 + (size_t)i * 32 * ldbB, sB + (i * 4 + wave) * 1024);
        __syncthreads();   // vmcnt(0) drain: staged tile visible
        #pragma unroll
        for (int kk = 0; kk < 2; ++kk) {
            bf16x8 af[FM], bf[FN];
            #pragma unroll
            for (int f = 0; f < FM; ++f) {
                const int r = wrow + f * 16 + rl;
                af[f] = *(const bf16x8*)(sA + r * 128 + (((kk * 4 + g) ^ (r & 7)) << 4));
            }
            #pragma unroll
            for (int j = 0; j < FN; ++j) {
                const int r = wcol + j * 16 + rl;
                bf[j] = *(const bf16x8*)(sB + r * 128 + (((kk * 4 + g) ^ (r & 7)) << 4));
            }
            #pragma unroll
            for (int f = 0; f < FM; ++f)
                #pragma unroll
                for (int j = 0; j < FN; ++j)
                    acc[f * FN + j] = __builtin_amdgcn_mfma_f32_16x16x32_bf16(af[f], bf[j], acc[f * FN + j], 0, 0, 0);
        }
    }
}

// ---------------- QKV projection GEMM (128x128 tiles, LDS-staged) ----------------
// 1D grid 640 = 16 m-tiles x 40 n-tiles, XCD-swizzled (640 % 8 == 0, bijective).
// y: [0,16) Q tiles, [16,32) K tiles, [32,40) V tiles. Q pre-scaled by 1/sqrt(d)*log2e.
__global__ __launch_bounds__(256) void k_gemm_qkv(
        const short* __restrict__ Xb,
        const short* __restrict__ WqT, const short* __restrict__ WkT, const short* __restrict__ WvT,
        const float* __restrict__ bq, const float* __restrict__ bk, const float* __restrict__ bv,
        short* __restrict__ Qh, short* __restrict__ Kh, short* __restrict__ Vt) {
    __shared__ __align__(16) char sA[16384], sB[16384];
    int id = blockIdx.x;
    id = (id & 7) * 80 + (id >> 3);           // XCD-contiguous chunks
    const int mbase = (id % 16) * 128;
    const int y = id / 16;

    const short* Bt; const float* bias; int nbase; int which;
    if (y < 16)      { which = 0; Bt = WqT; bias = bq; nbase = y * 128; }
    else if (y < 32) { which = 1; Bt = WkT; bias = bk; nbase = (y - 16) * 128; }
    else             { which = 2; Bt = WvT; bias = bv; nbase = (y - 32) * 128; }

    f32x4 acc[16];
    #pragma unroll
    for (int i = 0; i < 16; ++i) acc[i] = (f32x4){0.f, 0.f, 0.f, 0.f};

    gemm_core<128, 128, 2, 2>((const char*)Xb + (size_t)mbase * 2048, 2048,
                              (const char*)Bt + (size_t)nbase * 2048, 2048,
                              EDIM, sA, sB, acc);

    const int lane = threadIdx.x & 63, wave = threadIdx.x >> 6;
    const int wr = (wave >> 1) * 64, wc = (wave & 1) * 64;
    const int rl = lane & 15, g = lane >> 4;
    const float qscale = 0.125f * 1.44269504088896f;
    #pragma unroll
    for (int i = 0; i < 4; ++i)
        #pragma unroll
        for (int j = 0; j < 4; ++j)
            #pragma unroll
            for (int jj = 0; jj < 4; ++jj) {
                int s = mbase + wr + i * 16 + g * 4 + jj;
                int n = nbase + wc + j * 16 + rl;
                float v = acc[i * 4 + j][jj] + bias[n];
                if (which == 0) v *= qscale;
                short b16 = (short)f2bf(v);
                if (which == 0)      Qh[((size_t)(n >> 7) * S_LEN + s) * 128 + (n & 127)] = b16;
                else if (which == 1) Kh[((size_t)(n >> 7) * S_LEN + s) * 128 + (n & 127)] = b16;
                else                 Vt[(size_t)n * S_LEN + s] = b16;
            }
}

// ---------------- differential flash attention, v4: LDS-staged shared KV ----------------
__global__ __launch_bounds__(256) void k_attn(
        const short* __restrict__ Qh, const short* __restrict__ Kh,
        const short* __restrict__ Vt, const float* __restrict__ lam_p,
        short* __restrict__ Ocat) {
    __shared__ __align__(16) char smem[65536];
    char* Kl = smem;            // 2 x 16KB  K tiles [64][128] bf16, row-swizzled
    char* Vl = smem + 32768;    // 2 x 8KB   V tiles [64 d][64 kv] bf16, row-swizzled
    char* Pl = smem + 49152;    // 4 waves x 4KB P buffers [2][16][64] bf16, swizzled

    const int lane = threadIdx.x & 63, wave = threadIdx.x >> 6;
    const int rl = lane & 15, g = lane >> 4;
    const int h = blockIdx.y;
    const int qbase = blockIdx.x * 64 + wave * 16;
    const int swz = (rl & 7) << 4;
    const int kx = rl & 7;

    const char* Kgb = (const char*)(Kh + (size_t)h * S_LEN * 128);
    const char* Vgb = (const char*)(Vt + (size_t)h * DHEAD * S_LEN);
    const short* Qp = Qh + (size_t)h * S_LEN * 128;
    char* Pb0 = Pl + wave * 4096;
    char* Pb1 = Pb0 + 2048;

    const int kofs0 = (lane >> 4) * 256 + (((lane & 15) ^ (lane >> 4)) << 4);
    const int kofs1 = (lane >> 4) * 256 + (((lane & 15) ^ ((lane >> 4) + 4)) << 4);
    const int vofs  = (lane >> 3) * 4096 + (((lane & 7) ^ (lane >> 3)) << 4);

    bf16x8 qf[2][2];
    #pragma unroll
    for (int p = 0; p < 2; ++p)
        #pragma unroll
        for (int kc = 0; kc < 2; ++kc)
            qf[p][kc] = *(const bf16x8*)&Qp[(size_t)(qbase + rl) * 128 + p * 64 + kc * 32 + g * 8];

    #pragma unroll
    for (int cc = 0; cc < 4; ++cc) {
        int c = wave * 4 + cc;
        load_lds16(Kgb + c * 1024 + ((cc & 1) ? kofs1 : kofs0), Kl + c * 1024);
    }
    #pragma unroll
    for (int cc = 0; cc < 2; ++cc) {
        int c = wave * 2 + cc;
        load_lds16(Vgb + (size_t)c * 32768 + vofs, Vl + c * 1024);
    }

    f32x4 acc[2][4];
    float m[2], l[2];
    #pragma unroll
    for (int p = 0; p < 2; ++p) {
        #pragma unroll
        for (int t = 0; t < 4; ++t) acc[p][t] = (f32x4){0.f, 0.f, 0.f, 0.f};
        m[p] = 0.f; l[p] = 0.f;
    }

    __syncthreads();

    const int NIT = S_LEN / 64;
    for (int it = 0; it < NIT; ++it) {
        const int cur = it & 1;
        if (it + 1 < NIT) {
            const size_t nkv = (size_t)(it + 1) * 64;
            char* kb = Kl + (cur ^ 1) * 16384;
            char* vb = Vl + (cur ^ 1) * 8192;
            #pragma unroll
            for (int cc = 0; cc < 4; ++cc) {
                int c = wave * 4 + cc;
                load_lds16(Kgb + nkv * 256 + c * 1024 + ((cc & 1) ? kofs1 : kofs0), kb + c * 1024);
            }
            #pragma unroll
            for (int cc = 0; cc < 2; ++cc) {
                int c = wave * 2 + cc;
                load_lds16(Vgb + (size_t)c * 32768 + nkv * 2 + vofs, vb + c * 1024);
            }
        }
        const char* kb = Kl + cur * 16384;
        const char* vb = Vl + cur * 8192;

        f32x4 sc[2][4];
        #pragma unroll
        for (int t = 0; t < 4; ++t) {
            #pragma unroll
            for (int p = 0; p < 2; ++p) {
                f32x4 z = (f32x4){0.f, 0.f, 0.f, 0.f};
                #pragma unroll
                for (int kc = 0; kc < 2; ++kc) {
                    bf16x8 kf = *(const bf16x8*)(kb + t * 4096 + rl * 256 + (((p * 8 + kc * 4 + g) ^ kx) << 4));
                    z = __builtin_amdgcn_mfma_f32_16x16x32_bf16(kf, qf[p][kc], z, 0, 0, 0);
                }
                sc[p][t] = z;
            }
        }

        float bm[2];
        #pragma unroll
        for (int p = 0; p < 2; ++p) {
            float mx = sc[p][0][0];
            #pragma unroll
            for (int t = 0; t < 4; ++t)
                #pragma unroll
                for (int jj = 0; jj < 4; ++jj)
                    mx = fmaxf(mx, sc[p][t][jj]);
            mx = fmaxf(mx, __shfl_xor(mx, 16, 64));
            mx = fmaxf(mx, __shfl_xor(mx, 32, 64));
            bm[p] = mx;
        }

        if (it == 0) {
            m[0] = bm[0]; m[1] = bm[1];
        } else if (!__all((bm[0] <= m[0] + 8.f) && (bm[1] <= m[1] + 8.f))) {
            #pragma unroll
            for (int p = 0; p < 2; ++p) {
                float mn = fmaxf(m[p], bm[p]);
                float fac = exp2f(m[p] - mn);
                l[p] *= fac; m[p] = mn;
                #pragma unroll
                for (int jj = 0; jj < 4; ++jj) {
                    float fq = __shfl(fac, g * 4 + jj, 64);
                    #pragma unroll
                    for (int t = 0; t < 4; ++t) acc[p][t][jj] *= fq;
                }
            }
        }

        #pragma unroll
        for (int p = 0; p < 2; ++p) {
            char* Pb = p ? Pb1 : Pb0;
            float rs = 0.f;
            #pragma unroll
            for (int t = 0; t < 4; ++t) {
                #pragma unroll
                for (int jjp = 0; jjp < 4; jjp += 2) {
                    float e0 = exp2f(sc[p][t][jjp]     - m[p]);
                    float e1 = exp2f(sc[p][t][jjp + 1] - m[p]);
                    rs += e0 + e1;
                    unsigned u;
                    asm("v_cvt_pk_bf16_f32 %0, %1, %2" : "=v"(u) : "v"(e0), "v"(e1));
                    *(unsigned*)(Pb + rl * 128 + (((t * 16 + g * 4 + jjp) * 2) ^ swz)) = u;
                }
            }
            rs += __shfl_xor(rs, 16, 64);
            rs += __shfl_xor(rs, 32, 64);
            l[p] += rs;
        }

        #pragma unroll
        for (int kc = 0; kc < 2; ++kc) {
            bf16x8 pa0 = *(const bf16x8*)(Pb0 + rl * 128 + ((kc * 64 + g * 16) ^ swz));
            bf16x8 pa1 = *(const bf16x8*)(Pb1 + rl * 128 + ((kc * 64 + g * 16) ^ swz));
            #pragma unroll
            for (int t = 0; t < 4; ++t) {
                bf16x8 vf = *(const bf16x8*)(vb + t * 2048 + rl * 128 + (((kc * 4 + g) ^ kx) << 4));
                acc[0][t] = __builtin_amdgcn_mfma_f32_16x16x32_bf16(pa0, vf, acc[0][t], 0, 0, 0);
                acc[1][t] = __builtin_amdgcn_mfma_f32_16x16x32_bf16(pa1, vf, acc[1][t], 0, 0, 0);
            }
        }
        __syncthreads();
    }

    const float lam = lam_p[0];
    float inv0[4], inv1[4];
    #pragma unroll
    for (int jj = 0; jj < 4; ++jj) {
        inv0[jj] = 1.0f / __shfl(l[0], g * 4 + jj, 64);
        inv1[jj] = lam  / __shfl(l[1], g * 4 + jj, 64);
    }
    #pragma unroll
    for (int t = 0; t < 4; ++t)
        #pragma unroll
        for (int jj = 0; jj < 4; ++jj) {
            float o = acc[0][t][jj] * inv0[jj] - acc[1][t][jj] * inv1[jj];
            int s = qbase + g * 4 + jj;
            Ocat[(size_t)s * 1024 + h * 64 + t * 16 + rl] = (short)f2bf(o);
        }
}

// ---------------- output projection GEMM (64x128 tiles, LDS-staged) ----------------
// 1D grid 256 = 32 m-tiles x 8 n-tiles, XCD-swizzled.
__global__ __launch_bounds__(256) void k_gemm_out(
        const short* __restrict__ Ocat, const short* __restrict__ WoT,
        const float* __restrict__ bo, float* __restrict__ Yws) {
    __shared__ __align__(16) char sA[8192], sB[16384];
    int id = blockIdx.x;
    id = (id & 7) * 32 + (id >> 3);
    const int mbase = (id % 32) * 64;
    const int nbase = (id / 32) * 128;

    f32x4 acc[8];
    #pragma unroll
    for (int i = 0; i < 8; ++i) acc[i] = (f32x4){0.f, 0.f, 0.f, 0.f};

    gemm_core<64, 128, 1, 4>((const char*)Ocat + (size_t)mbase * 2048, 2048,
                             (const char*)WoT + (size_t)nbase * 2048, 2048,
                             1024, sA, sB, acc);

    const int lane = threadIdx.x & 63, wave = threadIdx.x >> 6;
    const int rl = lane & 15, g = lane >> 4;
    #pragma unroll
    for (int f = 0; f < 4; ++f)
        #pragma unroll
        for (int j = 0; j < 2; ++j)
            #pragma unroll
            for (int jj = 0; jj < 4; ++jj) {
                int s = mbase + f * 16 + g * 4 + jj;
                int e = nbase + wave * 32 + j * 16 + rl;
                Yws[(size_t)s * 1024 + e] = acc[f * 2 + j][jj] + bo[e];
            }
}

// ---------------- LayerNorm + final scale ----------------
__global__ __launch_bounds__(256) void k_ln(
        const float* __restrict__ Yws, const float* __restrict__ gamma,
        const float* __restrict__ beta, float* __restrict__ out) {
    const int s = blockIdx.x;
    const int tid = threadIdx.x;
    f32x4 y = ((const f32x4*)(Yws + (size_t)s * 1024))[tid];
    float sum = y[0] + y[1] + y[2] + y[3];
    float sq  = y[0]*y[0] + y[1]*y[1] + y[2]*y[2] + y[3]*y[3];
    #pragma unroll
    for (int off = 1; off < 64; off <<= 1) {
        sum += __shfl_xor(sum, off, 64);
        sq  += __shfl_xor(sq,  off, 64);
    }
    __shared__ float ls[2][4];
    const int wave = tid >> 6, lane = tid & 63;
    if (lane == 0) { ls[0][wave] = sum; ls[1][wave] = sq; }
    __syncthreads();
    sum = ls[0][0] + ls[0][1] + ls[0][2] + ls[0][3];
    sq  = ls[1][0] + ls[1][1] + ls[1][2] + ls[1][3];
    const float mu = sum * (1.f / 1024.f);
    const float var = sq * (1.f / 1024.f) - mu * mu;
    const float rstd = rsqrtf(var + 1e-5f);
    f32x4 gg = ((const f32x4*)gamma)[tid];
    f32x4 bb = ((const f32x4*)beta)[tid];
    f32x4 o;
    #pragma unroll
    for (int k = 0; k < 4; ++k)
        o[k] = ((y[k] - mu) * rstd * gg[k] + bb[k]) * 0.2f;
    ((f32x4*)(out + (size_t)s * 1024))[tid] = o;
}

extern "C" void kernel_launch(void* const* d_in, const int* in_sizes, int n_in,
                              void* d_out, int out_size, void* d_ws, size_t ws_size,
                              hipStream_t stream) {
    const float* X     = (const float*)d_in[0];
    const float* Wq    = (const float*)d_in[1];
    const float* bq    = (const float*)d_in[2];
    const float* Wk    = (const float*)d_in[3];
    const float* bk    = (const float*)d_in[4];
    const float* Wv    = (const float*)d_in[5];
    const float* bv    = (const float*)d_in[6];
    const float* Wo    = (const float*)d_in[7];
    const float* bo    = (const float*)d_in[8];
    const float* gamma = (const float*)d_in[9];
    const float* beta  = (const float*)d_in[10];
    const float* lam   = (const float*)d_in[11];
    float* out = (float*)d_out;

    char* ws = (char*)d_ws;
    const size_t MB = 1u << 20;
    short* Xb  = (short*)(ws + 0);        // 4MB (dead after qkv gemm)
    short* WqT = (short*)(ws + 4 * MB);   // 4MB (dead after qkv gemm)
    short* WkT = (short*)(ws + 8 * MB);   // 4MB
    short* WvT = (short*)(ws + 12 * MB);  // 2MB
    short* WoT = (short*)(ws + 14 * MB);  // 2MB
    short* Qh  = (short*)(ws + 16 * MB);  // 8MB
    short* Kh  = (short*)(ws + 24 * MB);  // 8MB
    short* Vt  = (short*)(ws + 32 * MB);  // 4MB
    short* Oc  = (short*)(ws + 36 * MB);  // 4MB
    float* Yws = (float*)(ws + 0);        // 8MB, aliases Xb+WqT (both dead by then)

    k_convert_x<<<dim3(2048), dim3(256), 0, stream>>>(X, Xb, (S_LEN * EDIM) / 4);
    k_transpose_cvt<<<dim3(4, 32, 16), dim3(32, 8), 0, stream>>>(Wq, WqT, 1024, 128);
    k_transpose_cvt<<<dim3(4, 32, 16), dim3(32, 8), 0, stream>>>(Wk, WkT, 1024, 128);
    k_transpose_cvt<<<dim3(2, 32, 16), dim3(32, 8), 0, stream>>>(Wv, WvT, 1024, 64);
    k_transpose_cvt<<<dim3(32, 32, 1), dim3(32, 8), 0, stream>>>(Wo, WoT, 1024, 1024);
    k_gemm_qkv<<<dim3(640), dim3(256), 0, stream>>>(Xb, WqT, WkT, WvT, bq, bk, bv, Qh, Kh, Vt);
    k_attn<<<dim3(32, 16), dim3(256), 0, stream>>>(Qh, Kh, Vt, lam, Oc);
    k_gemm_out<<<dim3(256), dim3(256), 0, stream>>>(Oc, WoT, bo, Yws);
    k_ln<<<dim3(2048), dim3(256), 0, stream>>>(Yws, gamma, beta, out);
}

// Round 6
// 172.959 us; speedup vs baseline: 2.3640x; 1.0296x over previous
//
#include <hip/hip_runtime.h>

#define S_LEN 2048
#define EDIM  1024
#define HEADS 16
#define DHEAD 64

typedef __attribute__((ext_vector_type(8))) short bf16x8;
typedef __attribute__((ext_vector_type(4))) short short4v;
typedef __attribute__((ext_vector_type(4))) float f32x4;

__device__ inline unsigned short f2bf(float f) {
    unsigned int u = __float_as_uint(f);
    unsigned int r = (u + 0x7FFFu + ((u >> 16) & 1u)) >> 16;
    return (unsigned short)r;
}
__device__ inline float bf2f(unsigned short b) {
    return __uint_as_float(((unsigned int)b) << 16);
}
__device__ inline void load_lds16(const void* g, void* l) {
    __builtin_amdgcn_global_load_lds(
        (const __attribute__((address_space(1))) unsigned int*)g,
        (__attribute__((address_space(3))) unsigned int*)l, 16, 0, 0);
}

// ---------------- X fp32 -> bf16 ----------------
__global__ void k_convert_x(const float* __restrict__ x, short* __restrict__ xb, int n4) {
    int i = blockIdx.x * blockDim.x + threadIdx.x;
    if (i >= n4) return;
    f32x4 v = ((const f32x4*)x)[i];
    short4v o;
    o[0] = (short)f2bf(v[0]); o[1] = (short)f2bf(v[1]);
    o[2] = (short)f2bf(v[2]); o[3] = (short)f2bf(v[3]);
    ((short4v*)xb)[i] = o;
}

// ---------------- tiled transpose + fp32->bf16: in[R][C] -> out[C][R], batched over z ----------------
__global__ void k_transpose_cvt(const float* __restrict__ in, short* __restrict__ out, int R, int C) {
    __shared__ float tile[32][33];
    const int b = blockIdx.z;
    in  += (size_t)b * R * C;
    out += (size_t)b * R * C;
    const int c0 = blockIdx.x * 32, r0 = blockIdx.y * 32;
    #pragma unroll
    for (int yy = 0; yy < 4; ++yy) {
        int r = r0 + threadIdx.y + yy * 8, c = c0 + threadIdx.x;
        tile[threadIdx.y + yy * 8][threadIdx.x] = (r < R && c < C) ? in[(size_t)r * C + c] : 0.f;
    }
    __syncthreads();
    #pragma unroll
    for (int yy = 0; yy < 4; ++yy) {
        int c = c0 + threadIdx.y + yy * 8, r = r0 + threadIdx.x;
        if (c < C && r < R) out[(size_t)c * R + r] = (short)f2bf(tile[threadIdx.x][threadIdx.y + yy * 8]);
    }
}

// ---------------- LDS-staged MFMA GEMM core (m97 structure) ----------------
template<int BM, int BN, int WR, int WC>
__device__ inline void gemm_core(const char* Ag, int ldaB, const char* Bg, int ldbB,
                                 int K, char* sA, char* sB, f32x4* acc) {
    constexpr int FM = BM / (WR * 16), FN = BN / (WC * 16);
    constexpr int RA = BM / 32, RB = BN / 32;
    const int lane = threadIdx.x & 63, wave = threadIdx.x >> 6;
    const int rl = lane & 15, g = lane >> 4;
    const int wrow = (wave / WC) * (BM / WR);
    const int wcol = (wave % WC) * (BN / WC);
    const int lr = lane >> 3;                 // row within 8-row staging group
    const int lc = ((lane & 7) ^ lr) << 4;    // inverse-swizzled 16B chunk
    const char* aSrc = Ag + (size_t)(wave * 8 + lr) * ldaB + lc;
    const char* bSrc = Bg + (size_t)(wave * 8 + lr) * ldbB + lc;

    for (int t = 0; t < K / 64; ++t) {
        __syncthreads();
        #pragma unroll
        for (int i = 0; i < RA; ++i)
            load_lds16(aSrc + (size_t)t * 128 + (size_t)i * 32 * ldaB, sA + (i * 4 + wave) * 1024);
        #pragma unroll
        for (int i = 0; i < RB; ++i)
            load_lds16(bSrc + (size_t)t * 128 + (size_t)i * 32 * ldbB, sB + (i * 4 + wave) * 1024);
        __syncthreads();
        #pragma unroll
        for (int kk = 0; kk < 2; ++kk) {
            bf16x8 af[FM], bf[FN];
            #pragma unroll
            for (int f = 0; f < FM; ++f) {
                const int r = wrow + f * 16 + rl;
                af[f] = *(const bf16x8*)(sA + r * 128 + (((kk * 4 + g) ^ (r & 7)) << 4));
            }
            #pragma unroll
            for (int j = 0; j < FN; ++j) {
                const int r = wcol + j * 16 + rl;
                bf[j] = *(const bf16x8*)(sB + r * 128 + (((kk * 4 + g) ^ (r & 7)) << 4));
            }
            #pragma unroll
            for (int f = 0; f < FM; ++f)
                #pragma unroll
                for (int j = 0; j < FN; ++j)
                    acc[f * FN + j] = __builtin_amdgcn_mfma_f32_16x16x32_bf16(af[f], bf[j], acc[f * FN + j], 0, 0, 0);
        }
    }
}

// ---------------- QKV projection GEMM (128x128 tiles, LDS-staged) ----------------
__global__ __launch_bounds__(256) void k_gemm_qkv(
        const short* __restrict__ Xb,
        const short* __restrict__ WqT, const short* __restrict__ WkT, const short* __restrict__ WvT,
        const float* __restrict__ bq, const float* __restrict__ bk, const float* __restrict__ bv,
        short* __restrict__ Qh, short* __restrict__ Kh, short* __restrict__ Vt) {
    __shared__ __align__(16) char sA[16384], sB[16384];
    int id = blockIdx.x;
    id = (id & 7) * 80 + (id >> 3);           // XCD-contiguous chunks
    const int mbase = (id % 16) * 128;
    const int y = id / 16;

    const short* Bt; const float* bias; int nbase; int which;
    if (y < 16)      { which = 0; Bt = WqT; bias = bq; nbase = y * 128; }
    else if (y < 32) { which = 1; Bt = WkT; bias = bk; nbase = (y - 16) * 128; }
    else             { which = 2; Bt = WvT; bias = bv; nbase = (y - 32) * 128; }

    f32x4 acc[16];
    #pragma unroll
    for (int i = 0; i < 16; ++i) acc[i] = (f32x4){0.f, 0.f, 0.f, 0.f};

    gemm_core<128, 128, 2, 2>((const char*)Xb + (size_t)mbase * 2048, 2048,
                              (const char*)Bt + (size_t)nbase * 2048, 2048,
                              EDIM, sA, sB, acc);

    const int lane = threadIdx.x & 63, wave = threadIdx.x >> 6;
    const int wr = (wave >> 1) * 64, wc = (wave & 1) * 64;
    const int rl = lane & 15, g = lane >> 4;
    const float qscale = 0.125f * 1.44269504088896f;
    #pragma unroll
    for (int i = 0; i < 4; ++i)
        #pragma unroll
        for (int j = 0; j < 4; ++j)
            #pragma unroll
            for (int jj = 0; jj < 4; ++jj) {
                int s = mbase + wr + i * 16 + g * 4 + jj;
                int n = nbase + wc + j * 16 + rl;
                float v = acc[i * 4 + j][jj] + bias[n];
                if (which == 0) v *= qscale;
                short b16 = (short)f2bf(v);
                if (which == 0)      Qh[((size_t)(n >> 7) * S_LEN + s) * 128 + (n & 127)] = b16;
                else if (which == 1) Kh[((size_t)(n >> 7) * S_LEN + s) * 128 + (n & 127)] = b16;
                else                 Vt[(size_t)n * S_LEN + s] = b16;
            }
}

// ---------------- differential flash attention, v5: 8-wave in-block KV split ----------------
// grid (S/64, H), 512 threads. Waves 0-3: q-rows (w&3)*16.., kv [0,1024);
// waves 4-7: same q-rows, kv [1024,2048). Per-group single-buffered K/V LDS
// staging (2 barriers/iter; co-resident block hides the drain). Sequential
// softmax pairs p=0,1 share one 2KB P buffer per wave. In-block partial
// combine (bf16) at the end. LDS = 32K (K) + 16K (V) + 16K (P) = 64KB
// -> 2 blocks/CU = 4 waves/SIMD.
__global__ __launch_bounds__(512, 4) void k_attn(
        const short* __restrict__ Qh, const short* __restrict__ Kh,
        const short* __restrict__ Vt, const float* __restrict__ lam_p,
        short* __restrict__ Ocat) {
    __shared__ __align__(16) char smem[65536];

    const int lane = threadIdx.x & 63, wave = threadIdx.x >> 6;
    const int rl = lane & 15, g = lane >> 4;
    const int qw = wave & 3, kvg = wave >> 2;
    const int h = blockIdx.y;
    const int qbase = blockIdx.x * 64 + qw * 16;
    const int swz = (rl & 7) << 4;
    const int kx = rl & 7;

    char* Kl = smem + kvg * 16384;            // [64][256B] K tile (this group)
    char* Vl = smem + 32768 + kvg * 8192;     // [64 d][128B] V tile
    char* Pw = smem + 49152 + wave * 2048;    // [16][128B] P buffer (per wave)

    const char* Kgb = (const char*)(Kh + (size_t)h * S_LEN * 128);
    const char* Vgb = (const char*)(Vt + (size_t)h * DHEAD * S_LEN);
    const short* Qp = Qh + (size_t)h * S_LEN * 128;

    // per-lane inverse-swizzled staging source offsets
    const int kofs0 = (lane >> 4) * 256 + (((lane & 15) ^ (lane >> 4)) << 4);
    const int kofs1 = (lane >> 4) * 256 + (((lane & 15) ^ ((lane >> 4) + 4)) << 4);
    const int vofs  = (lane >> 3) * 4096 + (((lane & 7) ^ (lane >> 3)) << 4);

    bf16x8 qf[2][2];
    #pragma unroll
    for (int p = 0; p < 2; ++p)
        #pragma unroll
        for (int kc = 0; kc < 2; ++kc)
            qf[p][kc] = *(const bf16x8*)&Qp[(size_t)(qbase + rl) * 128 + p * 64 + kc * 32 + g * 8];

    f32x4 acc[2][4];
    float m[2], l[2];
    #pragma unroll
    for (int p = 0; p < 2; ++p) {
        #pragma unroll
        for (int t = 0; t < 4; ++t) acc[p][t] = (f32x4){0.f, 0.f, 0.f, 0.f};
        m[p] = 0.f; l[p] = 0.f;
    }

    const int NIT = 1024 / 64;
    for (int it = 0; it < NIT; ++it) {
        const size_t kv0 = (size_t)(kvg * 1024 + it * 64);
        __syncthreads();   // previous iter's LDS reads drained
        #pragma unroll
        for (int cc = 0; cc < 4; ++cc) {
            int c = qw * 4 + cc;
            load_lds16(Kgb + kv0 * 256 + c * 1024 + ((cc & 1) ? kofs1 : kofs0), Kl + c * 1024);
        }
        #pragma unroll
        for (int cc = 0; cc < 2; ++cc) {
            int c = qw * 2 + cc;
            load_lds16(Vgb + (size_t)c * 32768 + kv0 * 2 + vofs, Vl + c * 1024);
        }
        __syncthreads();   // staged tile visible

        #pragma unroll
        for (int p = 0; p < 2; ++p) {
            // ---- QK^T (swapped: mfma(K,Q)); Q pre-scaled -> exp2 domain ----
            f32x4 sc[4];
            #pragma unroll
            for (int t = 0; t < 4; ++t) {
                f32x4 z = (f32x4){0.f, 0.f, 0.f, 0.f};
                #pragma unroll
                for (int kc = 0; kc < 2; ++kc) {
                    bf16x8 kf = *(const bf16x8*)(Kl + t * 4096 + rl * 256 + (((p * 8 + kc * 4 + g) ^ kx) << 4));
                    z = __builtin_amdgcn_mfma_f32_16x16x32_bf16(kf, qf[p][kc], z, 0, 0, 0);
                }
                sc[t] = z;
            }

            // ---- block max per q-row ----
            float mx = sc[0][0];
            #pragma unroll
            for (int t = 0; t < 4; ++t)
                #pragma unroll
                for (int jj = 0; jj < 4; ++jj)
                    mx = fmaxf(mx, sc[t][jj]);
            mx = fmaxf(mx, __shfl_xor(mx, 16, 64));
            mx = fmaxf(mx, __shfl_xor(mx, 32, 64));

            if (it == 0) {
                m[p] = mx;
            } else if (!__all(mx <= m[p] + 8.f)) {
                float mn = fmaxf(m[p], mx);
                float fac = exp2f(m[p] - mn);
                l[p] *= fac; m[p] = mn;
                #pragma unroll
                for (int jj = 0; jj < 4; ++jj) {
                    float fq = __shfl(fac, g * 4 + jj, 64);
                    #pragma unroll
                    for (int t = 0; t < 4; ++t) acc[p][t][jj] *= fq;
                }
            }

            // ---- P = exp2(S - m): packed cvt writes + lane-local row sum ----
            float rs = 0.f;
            #pragma unroll
            for (int t = 0; t < 4; ++t) {
                #pragma unroll
                for (int jjp = 0; jjp < 4; jjp += 2) {
                    float e0 = exp2f(sc[t][jjp]     - m[p]);
                    float e1 = exp2f(sc[t][jjp + 1] - m[p]);
                    rs += e0 + e1;
                    unsigned u;
                    asm("v_cvt_pk_bf16_f32 %0, %1, %2" : "=v"(u) : "v"(e0), "v"(e1));
                    *(unsigned*)(Pw + rl * 128 + (((t * 16 + g * 4 + jjp) * 2) ^ swz)) = u;
                }
            }
            rs += __shfl_xor(rs, 16, 64);
            rs += __shfl_xor(rs, 32, 64);
            l[p] += rs;

            // ---- O += P @ V (wave-private P; staged V) ----
            #pragma unroll
            for (int kc = 0; kc < 2; ++kc) {
                bf16x8 pa = *(const bf16x8*)(Pw + rl * 128 + ((kc * 64 + g * 16) ^ swz));
                #pragma unroll
                for (int t = 0; t < 4; ++t) {
                    bf16x8 vf = *(const bf16x8*)(Vl + t * 2048 + rl * 128 + (((kc * 4 + g) ^ kx) << 4));
                    acc[p][t] = __builtin_amdgcn_mfma_f32_16x16x32_bf16(pa, vf, acc[p][t], 0, 0, 0);
                }
            }
        }
    }

    // ---- exchange partials through LDS (all of smem is dead after barrier) ----
    __syncthreads();
    {
        unsigned short* Xw = (unsigned short*)(smem + wave * 4096);  // [2][16][64] bf16
        float* ML = (float*)(smem + 32768);                          // [8w][2p][{m,l}][16]
        #pragma unroll
        for (int p = 0; p < 2; ++p) {
            #pragma unroll
            for (int t = 0; t < 4; ++t)
                #pragma unroll
                for (int jj = 0; jj < 4; ++jj)
                    Xw[p * 1024 + (g * 4 + jj) * 64 + t * 16 + rl] = f2bf(acc[p][t][jj]);
            if (g == 0) {
                ML[(wave * 2 + p) * 32 + rl]      = m[p];
                ML[(wave * 2 + p) * 32 + 16 + rl] = l[p];
            }
        }
    }
    __syncthreads();

    // ---- combine the 2 kv-group partials; thread -> (q = tid>>3, d0 = (tid&7)*8) ----
    {
        const int q = threadIdx.x >> 3, d0 = (threadIdx.x & 7) * 8;
        const int q15 = q & 15, wa = q >> 4, wb = (q >> 4) + 4;
        const float* ML = (const float*)(smem + 32768);
        const float lam = lam_p[0];
        float res[2][8];
        float invL[2];
        #pragma unroll
        for (int p = 0; p < 2; ++p) {
            float ma = ML[(wa * 2 + p) * 32 + q15], la = ML[(wa * 2 + p) * 32 + 16 + q15];
            float mb = ML[(wb * 2 + p) * 32 + q15], lb = ML[(wb * 2 + p) * 32 + 16 + q15];
            float ms = fmaxf(ma, mb);
            float fa = exp2f(ma - ms), fb = exp2f(mb - ms);
            invL[p] = 1.0f / (fa * la + fb * lb);
            const unsigned short* xa = (const unsigned short*)(smem + wa * 4096 + p * 2048 + q15 * 128 + d0 * 2);
            const unsigned short* xb = (const unsigned short*)(smem + wb * 4096 + p * 2048 + q15 * 128 + d0 * 2);
            #pragma unroll
            for (int k = 0; k < 8; ++k)
                res[p][k] = fa * bf2f(xa[k]) + fb * bf2f(xb[k]);
        }
        bf16x8 ov;
        #pragma unroll
        for (int k = 0; k < 8; ++k)
            ov[k] = (short)f2bf(res[0][k] * invL[0] - lam * res[1][k] * invL[1]);
        *(bf16x8*)&Ocat[(size_t)(blockIdx.x * 64 + q) * 1024 + h * 64 + d0] = ov;
    }
}

// ---------------- output projection GEMM (64x128 tiles, LDS-staged) ----------------
__global__ __launch_bounds__(256) void k_gemm_out(
        const short* __restrict__ Ocat, const short* __restrict__ WoT,
        const float* __restrict__ bo, float* __restrict__ Yws) {
    __shared__ __align__(16) char sA[8192], sB[16384];
    int id = blockIdx.x;
    id = (id & 7) * 32 + (id >> 3);
    const int mbase = (id % 32) * 64;
    const int nbase = (id / 32) * 128;

    f32x4 acc[8];
    #pragma unroll
    for (int i = 0; i < 8; ++i) acc[i] = (f32x4){0.f, 0.f, 0.f, 0.f};

    gemm_core<64, 128, 1, 4>((const char*)Ocat + (size_t)mbase * 2048, 2048,
                             (const char*)WoT + (size_t)nbase * 2048, 2048,
                             1024, sA, sB, acc);

    const int lane = threadIdx.x & 63, wave = threadIdx.x >> 6;
    const int rl = lane & 15, g = lane >> 4;
    #pragma unroll
    for (int f = 0; f < 4; ++f)
        #pragma unroll
        for (int j = 0; j < 2; ++j)
            #pragma unroll
            for (int jj = 0; jj < 4; ++jj) {
                int s = mbase + f * 16 + g * 4 + jj;
                int e = nbase + wave * 32 + j * 16 + rl;
                Yws[(size_t)s * 1024 + e] = acc[f * 2 + j][jj] + bo[e];
            }
}

// ---------------- LayerNorm + final scale ----------------
__global__ __launch_bounds__(256) void k_ln(
        const float* __restrict__ Yws, const float* __restrict__ gamma,
        const float* __restrict__ beta, float* __restrict__ out) {
    const int s = blockIdx.x;
    const int tid = threadIdx.x;
    f32x4 y = ((const f32x4*)(Yws + (size_t)s * 1024))[tid];
    float sum = y[0] + y[1] + y[2] + y[3];
    float sq  = y[0]*y[0] + y[1]*y[1] + y[2]*y[2] + y[3]*y[3];
    #pragma unroll
    for (int off = 1; off < 64; off <<= 1) {
        sum += __shfl_xor(sum, off, 64);
        sq  += __shfl_xor(sq,  off, 64);
    }
    __shared__ float ls[2][4];
    const int wave = tid >> 6, lane = tid & 63;
    if (lane == 0) { ls[0][wave] = sum; ls[1][wave] = sq; }
    __syncthreads();
    sum = ls[0][0] + ls[0][1] + ls[0][2] + ls[0][3];
    sq  = ls[1][0] + ls[1][1] + ls[1][2] + ls[1][3];
    const float mu = sum * (1.f / 1024.f);
    const float var = sq * (1.f / 1024.f) - mu * mu;
    const float rstd = rsqrtf(var + 1e-5f);
    f32x4 gg = ((const f32x4*)gamma)[tid];
    f32x4 bb = ((const f32x4*)beta)[tid];
    f32x4 o;
    #pragma unroll
    for (int k = 0; k < 4; ++k)
        o[k] = ((y[k] - mu) * rstd * gg[k] + bb[k]) * 0.2f;
    ((f32x4*)(out + (size_t)s * 1024))[tid] = o;
}

extern "C" void kernel_launch(void* const* d_in, const int* in_sizes, int n_in,
                              void* d_out, int out_size, void* d_ws, size_t ws_size,
                              hipStream_t stream) {
    const float* X     = (const float*)d_in[0];
    const float* Wq    = (const float*)d_in[1];
    const float* bq    = (const float*)d_in[2];
    const float* Wk    = (const float*)d_in[3];
    const float* bk    = (const float*)d_in[4];
    const float* Wv    = (const float*)d_in[5];
    const float* bv    = (const float*)d_in[6];
    const float* Wo    = (const float*)d_in[7];
    const float* bo    = (const float*)d_in[8];
    const float* gamma = (const float*)d_in[9];
    const float* beta  = (const float*)d_in[10];
    const float* lam   = (const float*)d_in[11];
    float* out = (float*)d_out;

    char* ws = (char*)d_ws;
    const size_t MB = 1u << 20;
    short* Xb  = (short*)(ws + 0);        // 4MB (dead after qkv gemm)
    short* WqT = (short*)(ws + 4 * MB);   // 4MB (dead after qkv gemm)
    short* WkT = (short*)(ws + 8 * MB);   // 4MB
    short* WvT = (short*)(ws + 12 * MB);  // 2MB
    short* WoT = (short*)(ws + 14 * MB);  // 2MB
    short* Qh  = (short*)(ws + 16 * MB);  // 8MB
    short* Kh  = (short*)(ws + 24 * MB);  // 8MB
    short* Vt  = (short*)(ws + 32 * MB);  // 4MB
    short* Oc  = (short*)(ws + 36 * MB);  // 4MB
    float* Yws = (float*)(ws + 0);        // 8MB, aliases Xb+WqT (both dead by then)

    k_convert_x<<<dim3(2048), dim3(256), 0, stream>>>(X, Xb, (S_LEN * EDIM) / 4);
    k_transpose_cvt<<<dim3(4, 32, 16), dim3(32, 8), 0, stream>>>(Wq, WqT, 1024, 128);
    k_transpose_cvt<<<dim3(4, 32, 16), dim3(32, 8), 0, stream>>>(Wk, WkT, 1024, 128);
    k_transpose_cvt<<<dim3(2, 32, 16), dim3(32, 8), 0, stream>>>(Wv, WvT, 1024, 64);
    k_transpose_cvt<<<dim3(32, 32, 1), dim3(32, 8), 0, stream>>>(Wo, WoT, 1024, 1024);
    k_gemm_qkv<<<dim3(640), dim3(256), 0, stream>>>(Xb, WqT, WkT, WvT, bq, bk, bv, Qh, Kh, Vt);
    k_attn<<<dim3(32, 16), dim3(512), 0, stream>>>(Qh, Kh, Vt, lam, Oc);
    k_gemm_out<<<dim3(256), dim3(256), 0, stream>>>(Oc, WoT, bo, Yws);
    k_ln<<<dim3(2048), dim3(256), 0, stream>>>(Yws, gamma, beta, out);
}